// Round 7
// baseline (695.667 us; speedup 1.0000x reference)
//
#include <hip/hip_runtime.h>

#define THREADS 256

typedef __attribute__((ext_vector_type(8))) short short8;
typedef __attribute__((ext_vector_type(4))) float f32x4;
#define MFMA16(a, b, c) __builtin_amdgcn_mfma_f32_16x16x32_bf16(a, b, c, 0, 0, 0)

__device__ __forceinline__ unsigned short f2bf(float f) {
  unsigned int u = __float_as_uint(f);
  u += 0x7fffu + ((u >> 16) & 1u);
  return (unsigned short)(u >> 16);
}
__device__ __forceinline__ float bf2f(unsigned short h) {
  return __uint_as_float(((unsigned int)h) << 16);
}

// ---------------- bucket geometry ----------------
// Packed entry: ((dst & 255) << 17) | src   (src < 2^17 since N = 100000)
#define BSHIFT 8
#define BNODES (1 << BSHIFT)
#define NBMAX 512
#define EPT 16   // edges per thread in binning kernels; CHUNK = 4096
#define EPT2 16  // register-staged entries per thread in k_fill2
#define CAP 15360  // LDS-staged entries (60 KB); bucket mean 8192, sd ~90

// ---------------- pass A: edges per bucket ----------------
__global__ __launch_bounds__(THREADS) void k_bcount(const int* __restrict__ dst, int E,
                                                    int* __restrict__ bCnt) {
  __shared__ int lh[NBMAX];
  int t = threadIdx.x;
  for (int i = t; i < NBMAX; i += THREADS) lh[i] = 0;
  __syncthreads();
  int e0 = blockIdx.x * (THREADS * EPT);
#pragma unroll
  for (int j = 0; j < EPT; ++j) {
    int e = e0 + j * THREADS + t;
    if (e < E) atomicAdd(&lh[dst[e] >> BSHIFT], 1);
  }
  __syncthreads();
  for (int i = t; i < NBMAX; i += THREADS)
    if (lh[i]) atomicAdd(&bCnt[i], lh[i]);
}

// ---------------- pass B: scan bucket counts -> bOff (B+1 entries), zero bCur --------
__global__ __launch_bounds__(512) void k_bscan(const int* __restrict__ bCnt, int B,
                                               int* __restrict__ bOff, int* __restrict__ bCur) {
  __shared__ int sa[512], sb[512];
  int t = threadIdx.x;
  int v = (t < B) ? bCnt[t] : 0;
  sa[t] = v;
  __syncthreads();
  int* cur = sa; int* nxt = sb;
  for (int off = 1; off < 512; off <<= 1) {
    int val = cur[t];
    if (t >= off) val += cur[t - off];
    nxt[t] = val;
    __syncthreads();
    int* z = cur; cur = nxt; nxt = z;
  }
  if (t < B) {
    bOff[t] = cur[t] - v;   // exclusive
    bCur[t] = 0;
    if (t == B - 1) bOff[B] = cur[t];
  }
}

// ---------------- pass C: multi-split edges into bucket-contiguous tmp ---------------
__global__ __launch_bounds__(THREADS) void k_bin(const int* __restrict__ src,
                                                 const int* __restrict__ dst, int E, int n,
                                                 const int* __restrict__ bOff,
                                                 int* __restrict__ bCur,
                                                 unsigned int* __restrict__ tmp) {
  __shared__ int lh[NBMAX];
  __shared__ int gb[NBMAX];
  int t = threadIdx.x;
  int B = (n + BNODES - 1) >> BSHIFT;
  for (int i = t; i < NBMAX; i += THREADS) lh[i] = 0;
  __syncthreads();
  int e0 = blockIdx.x * (THREADS * EPT);
  int b[EPT]; int rk[EPT]; unsigned int v[EPT];
#pragma unroll
  for (int j = 0; j < EPT; ++j) {
    int e = e0 + j * THREADS + t;
    if (e < E) {
      int s = src[e], d = dst[e];
      b[j] = d >> BSHIFT;
      v[j] = ((unsigned int)(d & (BNODES - 1)) << 17) | (unsigned int)s;
      rk[j] = atomicAdd(&lh[b[j]], 1);
    } else {
      b[j] = -1;
    }
  }
  __syncthreads();
  for (int bb = t; bb < B; bb += THREADS) {
    int c = lh[bb];
    if (c > 0) gb[bb] = bOff[bb] + atomicAdd(&bCur[bb], c);
  }
  __syncthreads();
#pragma unroll
  for (int j = 0; j < EPT; ++j)
    if (b[j] >= 0) tmp[gb[b[j]] + rk[j]] = v[j];
}

// ---------------- pass D: per-bucket deg/dis/rowptr + LDS-staged CSR scatter ---------
// One block per bucket. Scatter happens in LDS; HBM sees coalesced read+write only.
// Each row's source list is then SORTED ascending: all concurrent waves in the agg
// kernels walk src-space in near-lockstep (order statistics of uniform samples), so
// the live gather window (~2-3 MB) fits per-XCD L2 -> FETCH_SIZE drops.
__global__ __launch_bounds__(1024) void k_fill2(const unsigned int* __restrict__ tmp,
                                                const int* __restrict__ bOff, int n,
                                                int* __restrict__ deg, float* __restrict__ dis,
                                                int* __restrict__ rowptr,
                                                int* __restrict__ csr) {
  __shared__ unsigned int buf[CAP];
  __shared__ int hist[BNODES];
  __shared__ int stmp[BNODES];
  __shared__ int excl[BNODES];
  int b = blockIdx.x;
  int node0 = b << BSHIFT;
  int t = threadIdx.x;
  int beg = bOff[b];
  int end = bOff[b + 1];
  int cnt = end - beg;
  if (t < BNODES) hist[t] = 0;
  __syncthreads();
  unsigned int v[EPT2];
  bool have[EPT2];
  bool inreg = (cnt <= CAP);
  if (inreg) {
#pragma unroll
    for (int j = 0; j < EPT2; ++j) {
      int i = j * 1024 + t;
      have[j] = (i < cnt);
      if (have[j]) {
        v[j] = tmp[beg + i];
        atomicAdd(&hist[v[j] >> 17], 1);
      }
    }
  } else {
    for (int i = t; i < cnt; i += 1024) atomicAdd(&hist[tmp[beg + i] >> 17], 1);
  }
  __syncthreads();
  int myDeg = (t < BNODES) ? hist[t] : 0;
  // inclusive scan of hist (256 lanes, full-block barriers)
  int* cur = hist; int* nxt = stmp;
  for (int off = 1; off < BNODES; off <<= 1) {
    if (t < BNODES) {
      int val = cur[t];
      if (t >= off) val += cur[t - off];
      nxt[t] = val;
    }
    __syncthreads();
    int* z = cur; cur = nxt; nxt = z;
  }
  if (t < BNODES) {
    int ex = cur[t] - myDeg;
    excl[t] = ex;
    int nd = node0 + t;
    if (nd < n) {
      deg[nd] = myDeg;
      dis[nd] = rsqrtf((float)(myDeg + 1));
      rowptr[nd] = beg + ex;
    }
  }
  __syncthreads();
  if (inreg) {
#pragma unroll
    for (int j = 0; j < EPT2; ++j)
      if (have[j]) {
        int pos = atomicAdd(&excl[v[j] >> 17], 1);
        buf[pos] = v[j] & 0x1FFFFu;
      }
    __syncthreads();
    // per-row insertion sort (deg ~32); excl[t] is now the row END after the atomics
    if (t < BNODES && myDeg > 1) {
      int hi = excl[t];
      int lo = hi - myDeg;
      for (int a = lo + 1; a < hi; ++a) {
        unsigned int key = buf[a];
        int q = a - 1;
        while (q >= lo && buf[q] > key) { buf[q + 1] = buf[q]; --q; }
        buf[q + 1] = key;
      }
    }
    __syncthreads();
    for (int i = t; i < cnt; i += 1024) csr[beg + i] = (int)buf[i];
  } else {
    // fallback: direct global scatter + sort using exact local offsets (rare)
    for (int i = t; i < cnt; i += 1024) {
      unsigned int u = tmp[beg + i];
      int pos = atomicAdd(&excl[u >> 17], 1);
      csr[beg + pos] = (int)(u & 0x1FFFFu);
    }
    __syncthreads();
    if (t < BNODES && myDeg > 1) {
      int hi = excl[t];
      int lo = hi - myDeg;
      for (int a = lo + 1; a < hi; ++a) {
        int key = csr[beg + a];
        int q = a - 1;
        while (q >= lo && csr[beg + q] > key) { csr[beg + q + 1] = csr[beg + q]; --q; }
        csr[beg + q + 1] = key;
      }
    }
  }
}

// ---------------- weight pack: MFMA B-fragment layout, bf16 ----------------
// WzP/WcP: [ct=16][ks=4][lane=64][8]  value = W[k = ks*32+quad*8+j][n = ct*16+l16]
// WoP:     [ct=8][kc=16][lane=64][8]  value = Wo[k = kc*32+quad*8+j][n = ct*16+l16]
__global__ void k_tw(const float* __restrict__ Wz, const float* __restrict__ Wc,
                     const float* __restrict__ Wo, unsigned short* __restrict__ WzP,
                     unsigned short* __restrict__ WcP, unsigned short* __restrict__ WoP) {
  int t = blockIdx.x * THREADS + threadIdx.x;
  if (t < 32768) {
    int ct = t >> 11, rem = t & 2047;
    int ks = rem >> 9, rem2 = rem & 511;
    int lane = rem2 >> 3, j = rem2 & 7;
    int l16 = lane & 15, quad = lane >> 4;
    int k = ks * 32 + quad * 8 + j;
    int nn = ct * 16 + l16;
    WzP[t] = f2bf(Wz[k * 256 + nn]);
    WcP[t] = f2bf(Wc[k * 256 + nn]);
  } else if (t < 32768 + 65536) {
    int u = t - 32768;
    int ct = u >> 13, rem = u & 8191;
    int kc = rem >> 9, rem2 = rem & 511;
    int lane = rem2 >> 3, j = rem2 & 7;
    int l16 = lane & 15, quad = lane >> 4;
    int k = kc * 32 + quad * 8 + j;
    int nn = ct * 16 + l16;
    WoP[u] = f2bf(Wo[k * 128 + nn]);
  }
}

// ---------------- cast: XB[s] = int8( dis[s]*x / S[s] ) + 128, S = rowmax/127 --------
__global__ void k_cast(const float4* __restrict__ lat4, const float4* __restrict__ con4,
                       const float* __restrict__ dis, unsigned int* __restrict__ XB8,
                       float* __restrict__ S, int n) {
  int tid = threadIdx.x;
  int d = blockIdx.x * 4 + (tid >> 6);
  if (d >= n) return;
  int li = tid & 63;
  float w = dis[d];
  float4 v = (li < 32) ? lat4[(size_t)d * 32 + li] : con4[(size_t)d * 32 + (li - 32)];
  v.x *= w; v.y *= w; v.z *= w; v.w *= w;
  float m = fmaxf(fmaxf(fabsf(v.x), fabsf(v.y)), fmaxf(fabsf(v.z), fabsf(v.w)));
#pragma unroll
  for (int off = 1; off < 64; off <<= 1) m = fmaxf(m, __shfl_xor(m, off, 64));
  m = fmaxf(m, 1e-20f);
  float inv = 127.0f / m;
  unsigned int u0 = (unsigned int)(int)rintf(v.x * inv) + 128u;
  unsigned int u1 = (unsigned int)(int)rintf(v.y * inv) + 128u;
  unsigned int u2 = (unsigned int)(int)rintf(v.z * inv) + 128u;
  unsigned int u3 = (unsigned int)(int)rintf(v.w * inv) + 128u;
  XB8[(size_t)d * 64 + li] = u0 | (u1 << 8) | (u2 << 16) | (u3 << 24);
  if (li == 0) S[d] = m * (1.0f / 127.0f);
}

// ---------------- agg1: Y[d] = bf16( dis[d]*(sum_e x[s] + x[d]) ), x int8+scale -------
// 2 dst rows per wave: row0's 8 gathers + row1's 8 independent gathers issued before
// either FMA block -> ~16 outstanding vmem per wave at modest VGPR, high occupancy.
__global__ void k_agg1(const unsigned int* __restrict__ XB8, const float* __restrict__ S,
                       const int* __restrict__ rowptr, const int* __restrict__ deg,
                       const int* __restrict__ csr, const float* __restrict__ dis,
                       ushort4* __restrict__ Y4, int n) {
  int tid = threadIdx.x;
  int d0v = blockIdx.x * 8 + (tid >> 6) * 2;
  if (d0v >= n) return;
  int d0 = __builtin_amdgcn_readfirstlane(d0v);
  int d1 = d0 + 1;
  int has1 = (d1 < n);
  int li = tid & 63;
  float a00 = 0.f, a01 = 0.f, a02 = 0.f, a03 = 0.f, ss0 = 0.f;
  float a10 = 0.f, a11 = 0.f, a12 = 0.f, a13 = 0.f, ss1 = 0.f;
  int beg0 = __builtin_amdgcn_readfirstlane(rowptr[d0]);
  int end0 = beg0 + __builtin_amdgcn_readfirstlane(deg[d0]);
  int beg1 = beg0, end1 = beg0;
  if (has1) {
    beg1 = __builtin_amdgcn_readfirstlane(rowptr[d1]);
    end1 = beg1 + __builtin_amdgcn_readfirstlane(deg[d1]);
  }
  int nb0 = (end0 - beg0) >> 3;
  int nb1 = (end1 - beg1) >> 3;
  int nbm = nb0 > nb1 ? nb0 : nb1;
  int i0 = beg0, i1 = beg1;
  for (int blk = 0; blk < nbm; ++blk) {
    int do0 = blk < nb0, do1 = blk < nb1;
    int s0[8], s1[8];
    unsigned int v0[8], v1[8];
    float sc0[8], sc1[8];
    if (do0) {
#pragma unroll
      for (int j = 0; j < 8; ++j) s0[j] = __builtin_amdgcn_readfirstlane(csr[i0 + j]);
#pragma unroll
      for (int j = 0; j < 8; ++j) { v0[j] = XB8[(size_t)s0[j] * 64 + li]; sc0[j] = S[s0[j]]; }
    }
    if (do1) {
#pragma unroll
      for (int j = 0; j < 8; ++j) s1[j] = __builtin_amdgcn_readfirstlane(csr[i1 + j]);
#pragma unroll
      for (int j = 0; j < 8; ++j) { v1[j] = XB8[(size_t)s1[j] * 64 + li]; sc1[j] = S[s1[j]]; }
    }
    if (do0) {
#pragma unroll
      for (int j = 0; j < 8; ++j) {
        a00 = fmaf((float)(v0[j] & 255u), sc0[j], a00);
        a01 = fmaf((float)((v0[j] >> 8) & 255u), sc0[j], a01);
        a02 = fmaf((float)((v0[j] >> 16) & 255u), sc0[j], a02);
        a03 = fmaf((float)(v0[j] >> 24), sc0[j], a03);
        ss0 += sc0[j];
      }
      i0 += 8;
    }
    if (do1) {
#pragma unroll
      for (int j = 0; j < 8; ++j) {
        a10 = fmaf((float)(v1[j] & 255u), sc1[j], a10);
        a11 = fmaf((float)((v1[j] >> 8) & 255u), sc1[j], a11);
        a12 = fmaf((float)((v1[j] >> 16) & 255u), sc1[j], a12);
        a13 = fmaf((float)(v1[j] >> 24), sc1[j], a13);
        ss1 += sc1[j];
      }
      i1 += 8;
    }
  }
  for (; i0 < end0; ++i0) {
    int s = __builtin_amdgcn_readfirstlane(csr[i0]);
    unsigned int v = XB8[(size_t)s * 64 + li];
    float sc = S[s];
    a00 = fmaf((float)(v & 255u), sc, a00);
    a01 = fmaf((float)((v >> 8) & 255u), sc, a01);
    a02 = fmaf((float)((v >> 16) & 255u), sc, a02);
    a03 = fmaf((float)(v >> 24), sc, a03);
    ss0 += sc;
  }
  for (; i1 < end1; ++i1) {
    int s = __builtin_amdgcn_readfirstlane(csr[i1]);
    unsigned int v = XB8[(size_t)s * 64 + li];
    float sc = S[s];
    a10 = fmaf((float)(v & 255u), sc, a10);
    a11 = fmaf((float)((v >> 8) & 255u), sc, a11);
    a12 = fmaf((float)((v >> 16) & 255u), sc, a12);
    a13 = fmaf((float)(v >> 24), sc, a13);
    ss1 += sc;
  }
  // self terms + writeback
  {
    unsigned int v = XB8[(size_t)d0 * 64 + li];
    float sc = S[d0];
    a00 = fmaf((float)(v & 255u), sc, a00);
    a01 = fmaf((float)((v >> 8) & 255u), sc, a01);
    a02 = fmaf((float)((v >> 16) & 255u), sc, a02);
    a03 = fmaf((float)(v >> 24), sc, a03);
    ss0 += sc;
    float bias = 128.0f * ss0;
    float wd = dis[d0];
    ushort4 o;
    o.x = f2bf((a00 - bias) * wd);
    o.y = f2bf((a01 - bias) * wd);
    o.z = f2bf((a02 - bias) * wd);
    o.w = f2bf((a03 - bias) * wd);
    Y4[(size_t)d0 * 64 + li] = o;
  }
  if (has1) {
    unsigned int v = XB8[(size_t)d1 * 64 + li];
    float sc = S[d1];
    a10 = fmaf((float)(v & 255u), sc, a10);
    a11 = fmaf((float)((v >> 8) & 255u), sc, a11);
    a12 = fmaf((float)((v >> 16) & 255u), sc, a12);
    a13 = fmaf((float)(v >> 24), sc, a13);
    ss1 += sc;
    float bias = 128.0f * ss1;
    float wd = dis[d1];
    ushort4 o;
    o.x = f2bf((a10 - bias) * wd);
    o.y = f2bf((a11 - bias) * wd);
    o.z = f2bf((a12 - bias) * wd);
    o.w = f2bf((a13 - bias) * wd);
    Y4[(size_t)d1 * 64 + li] = o;
  }
}

// ---------------- GEMM1 (MFMA): H = tanh([Yz@Wz + bz | Yc@Wc + bc]) bf16 -------------
// Y bf16 [N,256]; WzP/WcP packed B-frag; H bf16 [N,512]. 4 waves/block, 32 rows/wave.
__global__ __launch_bounds__(THREADS) void k_gemm1m(const unsigned short* __restrict__ Y,
                                                    unsigned short* __restrict__ H,
                                                    const unsigned short* __restrict__ WzP,
                                                    const unsigned short* __restrict__ WcP,
                                                    const float* __restrict__ bz,
                                                    const float* __restrict__ bc, int n) {
  int t = threadIdx.x;
  int wave = t >> 6, lane = t & 63;
  int quad = lane >> 4, l16 = lane & 15;
  int r0 = blockIdx.x * 128 + wave * 32;
  for (int half = 0; half < 2; ++half) {
    const unsigned short* WP = half ? WcP : WzP;
    const float* bias = half ? bc : bz;
    short8 a[2][4];
#pragma unroll
    for (int rg = 0; rg < 2; ++rg) {
      int row = r0 + rg * 16 + l16;
      if (row > n - 1) row = n - 1;
      const unsigned short* yp = Y + (size_t)row * 256 + half * 128 + quad * 8;
#pragma unroll
      for (int ks = 0; ks < 4; ++ks) a[rg][ks] = *(const short8*)(yp + ks * 32);
    }
    for (int ct = 0; ct < 16; ++ct) {
      f32x4 acc0 = {0.f, 0.f, 0.f, 0.f}, acc1 = {0.f, 0.f, 0.f, 0.f};
      const unsigned short* bp = WP + (size_t)(ct * 4) * 512 + lane * 8;
#pragma unroll
      for (int ks = 0; ks < 4; ++ks) {
        short8 b = *(const short8*)(bp + ks * 512);
        acc0 = MFMA16(a[0][ks], b, acc0);
        acc1 = MFMA16(a[1][ks], b, acc1);
      }
      int col = ct * 16 + l16;
      float bb = bias[col];
#pragma unroll
      for (int rg = 0; rg < 2; ++rg) {
        f32x4 ac = rg ? acc1 : acc0;
#pragma unroll
        for (int r = 0; r < 4; ++r) {
          int row = r0 + rg * 16 + quad * 4 + r;
          if (row < n) H[(size_t)row * 512 + half * 256 + col] = f2bf(tanhf(ac[r] + bb));
        }
      }
    }
  }
}

// ---------------- GEMM2 (MFMA): G3 = bf16( dis * (H @ Wo) ) --------------------------
// H bf16 [N,512]; WoP packed B-frag; G3 bf16 [N,128]. 4 waves/block, 32 rows/wave.
__global__ __launch_bounds__(THREADS) void k_gemm2m(const unsigned short* __restrict__ H,
                                                    const unsigned short* __restrict__ WoP,
                                                    const float* __restrict__ dis,
                                                    unsigned short* __restrict__ G3, int n) {
  int t = threadIdx.x;
  int wave = t >> 6, lane = t & 63;
  int quad = lane >> 4, l16 = lane & 15;
  int r0 = blockIdx.x * 128 + wave * 32;
  f32x4 acc[2][8];
#pragma unroll
  for (int rg = 0; rg < 2; ++rg)
#pragma unroll
    for (int ct = 0; ct < 8; ++ct) acc[rg][ct] = (f32x4){0.f, 0.f, 0.f, 0.f};
  int rowA0 = r0 + l16;        if (rowA0 > n - 1) rowA0 = n - 1;
  int rowA1 = r0 + 16 + l16;   if (rowA1 > n - 1) rowA1 = n - 1;
  const unsigned short* hp0 = H + (size_t)rowA0 * 512 + quad * 8;
  const unsigned short* hp1 = H + (size_t)rowA1 * 512 + quad * 8;
  for (int kc = 0; kc < 16; ++kc) {
    short8 a0 = *(const short8*)(hp0 + kc * 32);
    short8 a1 = *(const short8*)(hp1 + kc * 32);
#pragma unroll
    for (int ct = 0; ct < 8; ++ct) {
      short8 b = *(const short8*)(WoP + (size_t)(ct * 16 + kc) * 512 + lane * 8);
      acc[0][ct] = MFMA16(a0, b, acc[0][ct]);
      acc[1][ct] = MFMA16(a1, b, acc[1][ct]);
    }
  }
#pragma unroll
  for (int rg = 0; rg < 2; ++rg)
#pragma unroll
    for (int r = 0; r < 4; ++r) {
      int row = r0 + rg * 16 + quad * 4 + r;
      if (row < n) {
        float dd = dis[row];
#pragma unroll
        for (int ct = 0; ct < 8; ++ct)
          G3[(size_t)row * 128 + ct * 16 + l16] = f2bf(acc[rg][ct][r] * dd);
      }
    }
}

// ---------------- agg2: out[d] = dis[d]*(sum_e G3[s] + G3[d]) + bo, G3 bf16 ------------
// Same 2-rows-per-wave interleaved gather structure as k_agg1.
__global__ void k_agg2(const ushort2* __restrict__ G2, const int* __restrict__ rowptr,
                       const int* __restrict__ deg, const int* __restrict__ csr,
                       const float* __restrict__ dis, const float* __restrict__ bo,
                       float2* __restrict__ out2, int n) {
  int tid = threadIdx.x;
  int d0v = blockIdx.x * 8 + (tid >> 6) * 2;
  if (d0v >= n) return;
  int d0 = __builtin_amdgcn_readfirstlane(d0v);
  int d1 = d0 + 1;
  int has1 = (d1 < n);
  int lane = tid & 63;
  float ax0 = 0.f, ay0 = 0.f, ax1 = 0.f, ay1 = 0.f;
  int beg0 = __builtin_amdgcn_readfirstlane(rowptr[d0]);
  int end0 = beg0 + __builtin_amdgcn_readfirstlane(deg[d0]);
  int beg1 = beg0, end1 = beg0;
  if (has1) {
    beg1 = __builtin_amdgcn_readfirstlane(rowptr[d1]);
    end1 = beg1 + __builtin_amdgcn_readfirstlane(deg[d1]);
  }
  int nb0 = (end0 - beg0) >> 3;
  int nb1 = (end1 - beg1) >> 3;
  int nbm = nb0 > nb1 ? nb0 : nb1;
  int i0 = beg0, i1 = beg1;
  for (int blk = 0; blk < nbm; ++blk) {
    int do0 = blk < nb0, do1 = blk < nb1;
    int s0[8], s1[8];
    ushort2 v0[8], v1[8];
    if (do0) {
#pragma unroll
      for (int j = 0; j < 8; ++j) s0[j] = __builtin_amdgcn_readfirstlane(csr[i0 + j]);
#pragma unroll
      for (int j = 0; j < 8; ++j) v0[j] = G2[(size_t)s0[j] * 64 + lane];
    }
    if (do1) {
#pragma unroll
      for (int j = 0; j < 8; ++j) s1[j] = __builtin_amdgcn_readfirstlane(csr[i1 + j]);
#pragma unroll
      for (int j = 0; j < 8; ++j) v1[j] = G2[(size_t)s1[j] * 64 + lane];
    }
    if (do0) {
#pragma unroll
      for (int j = 0; j < 8; ++j) { ax0 += bf2f(v0[j].x); ay0 += bf2f(v0[j].y); }
      i0 += 8;
    }
    if (do1) {
#pragma unroll
      for (int j = 0; j < 8; ++j) { ax1 += bf2f(v1[j].x); ay1 += bf2f(v1[j].y); }
      i1 += 8;
    }
  }
  for (; i0 < end0; ++i0) {
    int s = __builtin_amdgcn_readfirstlane(csr[i0]);
    ushort2 v = G2[(size_t)s * 64 + lane];
    ax0 += bf2f(v.x); ay0 += bf2f(v.y);
  }
  for (; i1 < end1; ++i1) {
    int s = __builtin_amdgcn_readfirstlane(csr[i1]);
    ushort2 v = G2[(size_t)s * 64 + lane];
    ax1 += bf2f(v.x); ay1 += bf2f(v.y);
  }
  float2 bb = ((const float2*)bo)[lane];
  {
    ushort2 vd = G2[(size_t)d0 * 64 + lane];
    float wd = dis[d0];
    float2 o;
    o.x = (ax0 + bf2f(vd.x)) * wd + bb.x;
    o.y = (ay0 + bf2f(vd.y)) * wd + bb.y;
    out2[(size_t)d0 * 64 + lane] = o;
  }
  if (has1) {
    ushort2 vd = G2[(size_t)d1 * 64 + lane];
    float wd = dis[d1];
    float2 o;
    o.x = (ax1 + bf2f(vd.x)) * wd + bb.x;
    o.y = (ay1 + bf2f(vd.y)) * wd + bb.y;
    out2[(size_t)d1 * 64 + lane] = o;
  }
}

extern "C" void kernel_launch(void* const* d_in, const int* in_sizes, int n_in,
                              void* d_out, int out_size, void* d_ws, size_t ws_size,
                              hipStream_t stream) {
  const float* latent    = (const float*)d_in[0];
  const float* condition = (const float*)d_in[1];
  const int*   edges     = (const int*)d_in[2];
  const float* Wz        = (const float*)d_in[3];
  const float* bz        = (const float*)d_in[4];
  const float* Wc        = (const float*)d_in[5];
  const float* bc        = (const float*)d_in[6];
  const float* Wo        = (const float*)d_in[7];
  const float* bo        = (const float*)d_in[8];
  float* out = (float*)d_out;

  int n = in_sizes[0] / 128;      // 100000
  int E = in_sizes[2] / 2;        // 3200000
  const int* src = edges;
  const int* dst = edges + E;

  auto align_up = [](size_t x) { return (x + 255) & ~(size_t)255; };
  char* p = (char*)d_ws;
  int* csr     = (int*)p;   p += align_up((size_t)E * 4);
  int* rowptr  = (int*)p;   p += align_up((size_t)n * 4);
  int* deg     = (int*)p;   p += align_up((size_t)n * 4);
  float* dis   = (float*)p; p += align_up((size_t)n * 4);
  float* S     = (float*)p; p += align_up((size_t)n * 4);
  int* part    = (int*)p;   p += 8192;   // bCnt[512] | bOff[513] | bCur[512]
  unsigned short* WzP = (unsigned short*)p; p += 32768 * 2;
  unsigned short* WcP = (unsigned short*)p; p += 32768 * 2;
  unsigned short* WoP = (unsigned short*)p; p += 65536 * 2;
  unsigned short* Y  = (unsigned short*)p; p += align_up((size_t)n * 256 * 2);
  char* R = p; p += 2 * align_up((size_t)n * 256 * 2);   // 102.4MB region
  unsigned int* XB   = (unsigned int*)R;    // [N,64] u32 (int8 rows, 25.6MB)
  unsigned short* H  = (unsigned short*)R;  // [N,512] bf16 (102.4MB), aliases XB (dead)
  unsigned short* G3 = Y;                   // [N,128] bf16, aliases Y (dead after gemm1)
  unsigned int* tmpE = (unsigned int*)(R + (size_t)32 * 1024 * 1024); // binned edges,
                                            // 12.8MB, dead before H is written (gemm1)
  int* bCnt = part;
  int* bOff = part + 512;
  int* bCur = part + 1536;
  (void)ws_size; (void)n_in; (void)out_size;

  hipMemsetAsync(bCnt, 0, NBMAX * 4, stream);

  int g4 = (n + 3) / 4;
  int g8 = (n + 7) / 8;
  int gb = (n + 127) / 128;
  int B  = (n + BNODES - 1) >> BSHIFT;
  int gBin = (E + THREADS * EPT - 1) / (THREADS * EPT);

  k_bcount<<<gBin, THREADS, 0, stream>>>(dst, E, bCnt);
  k_bscan<<<1, 512, 0, stream>>>(bCnt, B, bOff, bCur);
  k_bin<<<gBin, THREADS, 0, stream>>>(src, dst, E, n, bOff, bCur, tmpE);
  k_fill2<<<B, 1024, 0, stream>>>(tmpE, bOff, n, deg, dis, rowptr, csr);
  k_tw<<<512, THREADS, 0, stream>>>(Wz, Wc, Wo, WzP, WcP, WoP);

  k_cast<<<g4, THREADS, 0, stream>>>((const float4*)latent, (const float4*)condition,
                                     dis, XB, S, n);
  k_agg1<<<g8, THREADS, 0, stream>>>(XB, S, rowptr, deg, csr, dis, (ushort4*)Y, n);
  k_gemm1m<<<gb, THREADS, 0, stream>>>(Y, H, WzP, WcP, bz, bc, n);
  k_gemm2m<<<gb, THREADS, 0, stream>>>(H, WoP, dis, G3, n);
  k_agg2<<<g8, THREADS, 0, stream>>>((const ushort2*)G3, rowptr, deg, csr, dis, bo,
                                     (float2*)out, n);
}

// Round 8
// 624.676 us; speedup vs baseline: 1.1136x; 1.1136x over previous
//
#include <hip/hip_runtime.h>

#define THREADS 256

typedef __attribute__((ext_vector_type(8))) short short8;
typedef __attribute__((ext_vector_type(4))) float f32x4;
#define MFMA16(a, b, c) __builtin_amdgcn_mfma_f32_16x16x32_bf16(a, b, c, 0, 0, 0)

__device__ __forceinline__ unsigned short f2bf(float f) {
  unsigned int u = __float_as_uint(f);
  u += 0x7fffu + ((u >> 16) & 1u);
  return (unsigned short)(u >> 16);
}
__device__ __forceinline__ float bf2f(unsigned short h) {
  return __uint_as_float(((unsigned int)h) << 16);
}
__device__ __forceinline__ float fast_tanh(float x) {
  // bf16-accurate: 1 - 2/(e^{2x}+1); rcp is v_rcp_f32 (~1ulp, invisible at bf16)
  float e = __expf(2.0f * x);
  return 1.0f - 2.0f * __builtin_amdgcn_rcpf(e + 1.0f);
}

// ---------------- bucket geometry ----------------
// Packed entry: ((dst & 255) << 17) | src   (src < 2^17 since N = 100000)
#define BSHIFT 8
#define BNODES (1 << BSHIFT)
#define NBMAX 512
#define EPT 16   // edges per thread in binning kernels; CHUNK = 4096
#define EPT2 16  // register-staged entries per thread in k_fill2
#define CAP 15360  // LDS-staged entries (60 KB); bucket mean 8192, sd ~90

// ---------------- pass A: edges per bucket ----------------
__global__ __launch_bounds__(THREADS) void k_bcount(const int* __restrict__ dst, int E,
                                                    int* __restrict__ bCnt) {
  __shared__ int lh[NBMAX];
  int t = threadIdx.x;
  for (int i = t; i < NBMAX; i += THREADS) lh[i] = 0;
  __syncthreads();
  int e0 = blockIdx.x * (THREADS * EPT);
#pragma unroll
  for (int j = 0; j < EPT; ++j) {
    int e = e0 + j * THREADS + t;
    if (e < E) atomicAdd(&lh[dst[e] >> BSHIFT], 1);
  }
  __syncthreads();
  for (int i = t; i < NBMAX; i += THREADS)
    if (lh[i]) atomicAdd(&bCnt[i], lh[i]);
}

// ---------------- pass B: scan bucket counts -> bOff (B+1 entries), zero bCur --------
__global__ __launch_bounds__(512) void k_bscan(const int* __restrict__ bCnt, int B,
                                               int* __restrict__ bOff, int* __restrict__ bCur) {
  __shared__ int sa[512], sb[512];
  int t = threadIdx.x;
  int v = (t < B) ? bCnt[t] : 0;
  sa[t] = v;
  __syncthreads();
  int* cur = sa; int* nxt = sb;
  for (int off = 1; off < 512; off <<= 1) {
    int val = cur[t];
    if (t >= off) val += cur[t - off];
    nxt[t] = val;
    __syncthreads();
    int* z = cur; cur = nxt; nxt = z;
  }
  if (t < B) {
    bOff[t] = cur[t] - v;   // exclusive
    bCur[t] = 0;
    if (t == B - 1) bOff[B] = cur[t];
  }
}

// ---------------- pass C: multi-split edges into bucket-contiguous tmp ---------------
__global__ __launch_bounds__(THREADS) void k_bin(const int* __restrict__ src,
                                                 const int* __restrict__ dst, int E, int n,
                                                 const int* __restrict__ bOff,
                                                 int* __restrict__ bCur,
                                                 unsigned int* __restrict__ tmp) {
  __shared__ int lh[NBMAX];
  __shared__ int gb[NBMAX];
  int t = threadIdx.x;
  int B = (n + BNODES - 1) >> BSHIFT;
  for (int i = t; i < NBMAX; i += THREADS) lh[i] = 0;
  __syncthreads();
  int e0 = blockIdx.x * (THREADS * EPT);
  int b[EPT]; int rk[EPT]; unsigned int v[EPT];
#pragma unroll
  for (int j = 0; j < EPT; ++j) {
    int e = e0 + j * THREADS + t;
    if (e < E) {
      int s = src[e], d = dst[e];
      b[j] = d >> BSHIFT;
      v[j] = ((unsigned int)(d & (BNODES - 1)) << 17) | (unsigned int)s;
      rk[j] = atomicAdd(&lh[b[j]], 1);
    } else {
      b[j] = -1;
    }
  }
  __syncthreads();
  for (int bb = t; bb < B; bb += THREADS) {
    int c = lh[bb];
    if (c > 0) gb[bb] = bOff[bb] + atomicAdd(&bCur[bb], c);
  }
  __syncthreads();
#pragma unroll
  for (int j = 0; j < EPT; ++j)
    if (b[j] >= 0) tmp[gb[b[j]] + rk[j]] = v[j];
}

// ---------------- pass D: per-bucket deg/dis/rowptr + LDS-staged CSR scatter ---------
// One block per bucket. Scatter happens in LDS; HBM sees coalesced read+write only.
// (round-7 per-row sort REVERTED: it cost 133us of LDS serialization and the agg
//  kernels showed zero fetch benefit -> lockstep-window theory falsified)
__global__ __launch_bounds__(1024) void k_fill2(const unsigned int* __restrict__ tmp,
                                                const int* __restrict__ bOff, int n,
                                                int* __restrict__ deg, float* __restrict__ dis,
                                                int* __restrict__ rowptr,
                                                int* __restrict__ csr) {
  __shared__ unsigned int buf[CAP];
  __shared__ int hist[BNODES];
  __shared__ int stmp[BNODES];
  __shared__ int excl[BNODES];
  int b = blockIdx.x;
  int node0 = b << BSHIFT;
  int t = threadIdx.x;
  int beg = bOff[b];
  int end = bOff[b + 1];
  int cnt = end - beg;
  if (t < BNODES) hist[t] = 0;
  __syncthreads();
  unsigned int v[EPT2];
  bool have[EPT2];
  bool inreg = (cnt <= CAP);
  if (inreg) {
#pragma unroll
    for (int j = 0; j < EPT2; ++j) {
      int i = j * 1024 + t;
      have[j] = (i < cnt);
      if (have[j]) {
        v[j] = tmp[beg + i];
        atomicAdd(&hist[v[j] >> 17], 1);
      }
    }
  } else {
    for (int i = t; i < cnt; i += 1024) atomicAdd(&hist[tmp[beg + i] >> 17], 1);
  }
  __syncthreads();
  int myDeg = (t < BNODES) ? hist[t] : 0;
  // inclusive scan of hist (256 lanes, full-block barriers)
  int* cur = hist; int* nxt = stmp;
  for (int off = 1; off < BNODES; off <<= 1) {
    if (t < BNODES) {
      int val = cur[t];
      if (t >= off) val += cur[t - off];
      nxt[t] = val;
    }
    __syncthreads();
    int* z = cur; cur = nxt; nxt = z;
  }
  if (t < BNODES) {
    int ex = cur[t] - myDeg;
    excl[t] = ex;
    int nd = node0 + t;
    if (nd < n) {
      deg[nd] = myDeg;
      dis[nd] = rsqrtf((float)(myDeg + 1));
      rowptr[nd] = beg + ex;
    }
  }
  __syncthreads();
  if (inreg) {
#pragma unroll
    for (int j = 0; j < EPT2; ++j)
      if (have[j]) {
        int pos = atomicAdd(&excl[v[j] >> 17], 1);
        buf[pos] = v[j] & 0x1FFFFu;
      }
    __syncthreads();
    for (int i = t; i < cnt; i += 1024) csr[beg + i] = (int)buf[i];
  } else {
    // fallback: direct global scatter using exact local offsets (rare)
    for (int i = t; i < cnt; i += 1024) {
      unsigned int u = tmp[beg + i];
      int pos = atomicAdd(&excl[u >> 17], 1);
      csr[beg + pos] = (int)(u & 0x1FFFFu);
    }
  }
}

// ---------------- weight pack: MFMA B-fragment layout, bf16 ----------------
// WzP/WcP: [ct=16][ks=4][lane=64][8]  value = W[k = ks*32+quad*8+j][n = ct*16+l16]
// WoP:     [ct=8][kc=16][lane=64][8]  value = Wo[k = kc*32+quad*8+j][n = ct*16+l16]
__global__ void k_tw(const float* __restrict__ Wz, const float* __restrict__ Wc,
                     const float* __restrict__ Wo, unsigned short* __restrict__ WzP,
                     unsigned short* __restrict__ WcP, unsigned short* __restrict__ WoP) {
  int t = blockIdx.x * THREADS + threadIdx.x;
  if (t < 32768) {
    int ct = t >> 11, rem = t & 2047;
    int ks = rem >> 9, rem2 = rem & 511;
    int lane = rem2 >> 3, j = rem2 & 7;
    int l16 = lane & 15, quad = lane >> 4;
    int k = ks * 32 + quad * 8 + j;
    int nn = ct * 16 + l16;
    WzP[t] = f2bf(Wz[k * 256 + nn]);
    WcP[t] = f2bf(Wc[k * 256 + nn]);
  } else if (t < 32768 + 65536) {
    int u = t - 32768;
    int ct = u >> 13, rem = u & 8191;
    int kc = rem >> 9, rem2 = rem & 511;
    int lane = rem2 >> 3, j = rem2 & 7;
    int l16 = lane & 15, quad = lane >> 4;
    int k = kc * 32 + quad * 8 + j;
    int nn = ct * 16 + l16;
    WoP[u] = f2bf(Wo[k * 128 + nn]);
  }
}

// ---------------- cast: XB[s] = int8( dis[s]*x / S[s] ) + 128, S = rowmax/127 --------
__global__ void k_cast(const float4* __restrict__ lat4, const float4* __restrict__ con4,
                       const float* __restrict__ dis, unsigned int* __restrict__ XB8,
                       float* __restrict__ S, int n) {
  int tid = threadIdx.x;
  int d = blockIdx.x * 4 + (tid >> 6);
  if (d >= n) return;
  int li = tid & 63;
  float w = dis[d];
  float4 v = (li < 32) ? lat4[(size_t)d * 32 + li] : con4[(size_t)d * 32 + (li - 32)];
  v.x *= w; v.y *= w; v.z *= w; v.w *= w;
  float m = fmaxf(fmaxf(fabsf(v.x), fabsf(v.y)), fmaxf(fabsf(v.z), fabsf(v.w)));
#pragma unroll
  for (int off = 1; off < 64; off <<= 1) m = fmaxf(m, __shfl_xor(m, off, 64));
  m = fmaxf(m, 1e-20f);
  float inv = 127.0f / m;
  unsigned int u0 = (unsigned int)(int)rintf(v.x * inv) + 128u;
  unsigned int u1 = (unsigned int)(int)rintf(v.y * inv) + 128u;
  unsigned int u2 = (unsigned int)(int)rintf(v.z * inv) + 128u;
  unsigned int u3 = (unsigned int)(int)rintf(v.w * inv) + 128u;
  XB8[(size_t)d * 64 + li] = u0 | (u1 << 8) | (u2 << 16) | (u3 << 24);
  if (li == 0) S[d] = m * (1.0f / 127.0f);
}

// ---------------- agg1: Y[d] = bf16( dis[d]*(sum_e x[s] + x[d]) ), x int8+scale -------
// GRID-LEVEL FEATURE SPLIT: launched twice (pass=0,1). Pass p gathers only dword-half
// p of each XB row -> chip-wide live working set = 12.8MB in half the lines, doubling
// the L2 capacity ratio. Half-wave layout: lanes 0-31 = row d0's 128B half, lanes
// 32-63 = row d1's. Masked edges redirect to the hot self-row (no wasted fetch).
__global__ void k_agg1(const unsigned int* __restrict__ XB8, const float* __restrict__ S,
                       const int* __restrict__ rowptr, const int* __restrict__ deg,
                       const int* __restrict__ csr, const float* __restrict__ dis,
                       ushort4* __restrict__ Y4, int n, int E, int pass) {
  int tid = threadIdx.x;
  int d0v = blockIdx.x * 8 + (tid >> 6) * 2;
  if (d0v >= n) return;
  int d0 = __builtin_amdgcn_readfirstlane(d0v);
  int has1 = (d0 + 1 < n);
  int d1 = has1 ? d0 + 1 : d0;
  int li = tid & 63;
  int hw = li >> 5, lj = li & 31;
  int beg0 = __builtin_amdgcn_readfirstlane(rowptr[d0]);
  int cnt0 = __builtin_amdgcn_readfirstlane(deg[d0]);
  int beg1 = __builtin_amdgcn_readfirstlane(rowptr[d1]);
  int cnt1 = has1 ? __builtin_amdgcn_readfirstlane(deg[d1]) : 0;
  int dh = hw ? d1 : d0;        // this lane's row (per-half)
  int cnth = hw ? cnt1 : cnt0;
  const unsigned int* XBp = XB8 + pass * 32;
  float a0 = 0.f, a1 = 0.f, a2 = 0.f, a3 = 0.f, ssum = 0.f;
  int nbm = cnt0 > cnt1 ? cnt0 : cnt1;
  for (int i = 0; i < nbm; i += 8) {
    int s0[8], s1[8];
#pragma unroll
    for (int j = 0; j < 8; ++j) {
      int i0 = beg0 + i + j; if (i0 > E - 1) i0 = E - 1;
      int i1 = beg1 + i + j; if (i1 > E - 1) i1 = E - 1;
      s0[j] = __builtin_amdgcn_readfirstlane(csr[i0]);
      s1[j] = __builtin_amdgcn_readfirstlane(csr[i1]);
    }
    unsigned int v[8]; float sc[8];
#pragma unroll
    for (int j = 0; j < 8; ++j) {
      bool valid = (i + j) < cnth;
      int sv = hw ? s1[j] : s0[j];
      sv = valid ? sv : dh;           // masked -> hot self row, free fetch
      v[j] = XBp[(size_t)sv * 64 + lj];
      sc[j] = valid ? S[sv] : 0.f;
    }
#pragma unroll
    for (int j = 0; j < 8; ++j) {
      a0 = fmaf((float)(v[j] & 255u), sc[j], a0);
      a1 = fmaf((float)((v[j] >> 8) & 255u), sc[j], a1);
      a2 = fmaf((float)((v[j] >> 16) & 255u), sc[j], a2);
      a3 = fmaf((float)(v[j] >> 24), sc[j], a3);
      ssum += sc[j];
    }
  }
  // self term
  {
    unsigned int v = XBp[(size_t)dh * 64 + lj];
    float sc = (hw && !has1) ? 0.f : S[dh];
    a0 = fmaf((float)(v & 255u), sc, a0);
    a1 = fmaf((float)((v >> 8) & 255u), sc, a1);
    a2 = fmaf((float)((v >> 16) & 255u), sc, a2);
    a3 = fmaf((float)(v >> 24), sc, a3);
    ssum += sc;
  }
  float bias = 128.0f * ssum;
  float wd = dis[dh];
  ushort4 o;
  o.x = f2bf((a0 - bias) * wd);
  o.y = f2bf((a1 - bias) * wd);
  o.z = f2bf((a2 - bias) * wd);
  o.w = f2bf((a3 - bias) * wd);
  if (!hw || has1) Y4[(size_t)dh * 64 + pass * 32 + lj] = o;
}

// ---------------- GEMM1 (MFMA): H = tanh([Yz@Wz + bz | Yc@Wc + bc]) bf16 -------------
// Y bf16 [N,256]; WzP/WcP packed B-frag; H bf16 [N,512]. 4 waves/block, 32 rows/wave.
__global__ __launch_bounds__(THREADS) void k_gemm1m(const unsigned short* __restrict__ Y,
                                                    unsigned short* __restrict__ H,
                                                    const unsigned short* __restrict__ WzP,
                                                    const unsigned short* __restrict__ WcP,
                                                    const float* __restrict__ bz,
                                                    const float* __restrict__ bc, int n) {
  int t = threadIdx.x;
  int wave = t >> 6, lane = t & 63;
  int quad = lane >> 4, l16 = lane & 15;
  int r0 = blockIdx.x * 128 + wave * 32;
  for (int half = 0; half < 2; ++half) {
    const unsigned short* WP = half ? WcP : WzP;
    const float* bias = half ? bc : bz;
    short8 a[2][4];
#pragma unroll
    for (int rg = 0; rg < 2; ++rg) {
      int row = r0 + rg * 16 + l16;
      if (row > n - 1) row = n - 1;
      const unsigned short* yp = Y + (size_t)row * 256 + half * 128 + quad * 8;
#pragma unroll
      for (int ks = 0; ks < 4; ++ks) a[rg][ks] = *(const short8*)(yp + ks * 32);
    }
    for (int ct = 0; ct < 16; ++ct) {
      f32x4 acc0 = {0.f, 0.f, 0.f, 0.f}, acc1 = {0.f, 0.f, 0.f, 0.f};
      const unsigned short* bp = WP + (size_t)(ct * 4) * 512 + lane * 8;
#pragma unroll
      for (int ks = 0; ks < 4; ++ks) {
        short8 b = *(const short8*)(bp + ks * 512);
        acc0 = MFMA16(a[0][ks], b, acc0);
        acc1 = MFMA16(a[1][ks], b, acc1);
      }
      int col = ct * 16 + l16;
      float bb = bias[col];
#pragma unroll
      for (int rg = 0; rg < 2; ++rg) {
        f32x4 ac = rg ? acc1 : acc0;
#pragma unroll
        for (int r = 0; r < 4; ++r) {
          int row = r0 + rg * 16 + quad * 4 + r;
          if (row < n) H[(size_t)row * 512 + half * 256 + col] = f2bf(fast_tanh(ac[r] + bb));
        }
      }
    }
  }
}

// ---------------- GEMM2 (MFMA): G3 = bf16( dis * (H @ Wo) ) --------------------------
// H bf16 [N,512]; WoP packed B-frag; G3 bf16 [N,128]. 4 waves/block, 32 rows/wave.
__global__ __launch_bounds__(THREADS) void k_gemm2m(const unsigned short* __restrict__ H,
                                                    const unsigned short* __restrict__ WoP,
                                                    const float* __restrict__ dis,
                                                    unsigned short* __restrict__ G3, int n) {
  int t = threadIdx.x;
  int wave = t >> 6, lane = t & 63;
  int quad = lane >> 4, l16 = lane & 15;
  int r0 = blockIdx.x * 128 + wave * 32;
  f32x4 acc[2][8];
#pragma unroll
  for (int rg = 0; rg < 2; ++rg)
#pragma unroll
    for (int ct = 0; ct < 8; ++ct) acc[rg][ct] = (f32x4){0.f, 0.f, 0.f, 0.f};
  int rowA0 = r0 + l16;        if (rowA0 > n - 1) rowA0 = n - 1;
  int rowA1 = r0 + 16 + l16;   if (rowA1 > n - 1) rowA1 = n - 1;
  const unsigned short* hp0 = H + (size_t)rowA0 * 512 + quad * 8;
  const unsigned short* hp1 = H + (size_t)rowA1 * 512 + quad * 8;
  for (int kc = 0; kc < 16; ++kc) {
    short8 a0 = *(const short8*)(hp0 + kc * 32);
    short8 a1 = *(const short8*)(hp1 + kc * 32);
#pragma unroll
    for (int ct = 0; ct < 8; ++ct) {
      short8 b = *(const short8*)(WoP + (size_t)(ct * 16 + kc) * 512 + lane * 8);
      acc[0][ct] = MFMA16(a0, b, acc[0][ct]);
      acc[1][ct] = MFMA16(a1, b, acc[1][ct]);
    }
  }
#pragma unroll
  for (int rg = 0; rg < 2; ++rg)
#pragma unroll
    for (int r = 0; r < 4; ++r) {
      int row = r0 + rg * 16 + quad * 4 + r;
      if (row < n) {
        float dd = dis[row];
#pragma unroll
        for (int ct = 0; ct < 8; ++ct)
          G3[(size_t)row * 128 + ct * 16 + l16] = f2bf(acc[rg][ct][r] * dd);
      }
    }
}

// ---------------- agg2: out[d] = dis[d]*(sum_e G3[s] + G3[d]) + bo, G3 bf16 ------------
// Same 2-rows-per-wave interleaved gather structure as round-6 k_agg1.
__global__ void k_agg2(const ushort2* __restrict__ G2, const int* __restrict__ rowptr,
                       const int* __restrict__ deg, const int* __restrict__ csr,
                       const float* __restrict__ dis, const float* __restrict__ bo,
                       float2* __restrict__ out2, int n) {
  int tid = threadIdx.x;
  int d0v = blockIdx.x * 8 + (tid >> 6) * 2;
  if (d0v >= n) return;
  int d0 = __builtin_amdgcn_readfirstlane(d0v);
  int d1 = d0 + 1;
  int has1 = (d1 < n);
  int lane = tid & 63;
  float ax0 = 0.f, ay0 = 0.f, ax1 = 0.f, ay1 = 0.f;
  int beg0 = __builtin_amdgcn_readfirstlane(rowptr[d0]);
  int end0 = beg0 + __builtin_amdgcn_readfirstlane(deg[d0]);
  int beg1 = beg0, end1 = beg0;
  if (has1) {
    beg1 = __builtin_amdgcn_readfirstlane(rowptr[d1]);
    end1 = beg1 + __builtin_amdgcn_readfirstlane(deg[d1]);
  }
  int nb0 = (end0 - beg0) >> 3;
  int nb1 = (end1 - beg1) >> 3;
  int nbm = nb0 > nb1 ? nb0 : nb1;
  int i0 = beg0, i1 = beg1;
  for (int blk = 0; blk < nbm; ++blk) {
    int do0 = blk < nb0, do1 = blk < nb1;
    int s0[8], s1[8];
    ushort2 v0[8], v1[8];
    if (do0) {
#pragma unroll
      for (int j = 0; j < 8; ++j) s0[j] = __builtin_amdgcn_readfirstlane(csr[i0 + j]);
#pragma unroll
      for (int j = 0; j < 8; ++j) v0[j] = G2[(size_t)s0[j] * 64 + lane];
    }
    if (do1) {
#pragma unroll
      for (int j = 0; j < 8; ++j) s1[j] = __builtin_amdgcn_readfirstlane(csr[i1 + j]);
#pragma unroll
      for (int j = 0; j < 8; ++j) v1[j] = G2[(size_t)s1[j] * 64 + lane];
    }
    if (do0) {
#pragma unroll
      for (int j = 0; j < 8; ++j) { ax0 += bf2f(v0[j].x); ay0 += bf2f(v0[j].y); }
      i0 += 8;
    }
    if (do1) {
#pragma unroll
      for (int j = 0; j < 8; ++j) { ax1 += bf2f(v1[j].x); ay1 += bf2f(v1[j].y); }
      i1 += 8;
    }
  }
  for (; i0 < end0; ++i0) {
    int s = __builtin_amdgcn_readfirstlane(csr[i0]);
    ushort2 v = G2[(size_t)s * 64 + lane];
    ax0 += bf2f(v.x); ay0 += bf2f(v.y);
  }
  for (; i1 < end1; ++i1) {
    int s = __builtin_amdgcn_readfirstlane(csr[i1]);
    ushort2 v = G2[(size_t)s * 64 + lane];
    ax1 += bf2f(v.x); ay1 += bf2f(v.y);
  }
  float2 bb = ((const float2*)bo)[lane];
  {
    ushort2 vd = G2[(size_t)d0 * 64 + lane];
    float wd = dis[d0];
    float2 o;
    o.x = (ax0 + bf2f(vd.x)) * wd + bb.x;
    o.y = (ay0 + bf2f(vd.y)) * wd + bb.y;
    out2[(size_t)d0 * 64 + lane] = o;
  }
  if (has1) {
    ushort2 vd = G2[(size_t)d1 * 64 + lane];
    float wd = dis[d1];
    float2 o;
    o.x = (ax1 + bf2f(vd.x)) * wd + bb.x;
    o.y = (ay1 + bf2f(vd.y)) * wd + bb.y;
    out2[(size_t)d1 * 64 + lane] = o;
  }
}

extern "C" void kernel_launch(void* const* d_in, const int* in_sizes, int n_in,
                              void* d_out, int out_size, void* d_ws, size_t ws_size,
                              hipStream_t stream) {
  const float* latent    = (const float*)d_in[0];
  const float* condition = (const float*)d_in[1];
  const int*   edges     = (const int*)d_in[2];
  const float* Wz        = (const float*)d_in[3];
  const float* bz        = (const float*)d_in[4];
  const float* Wc        = (const float*)d_in[5];
  const float* bc        = (const float*)d_in[6];
  const float* Wo        = (const float*)d_in[7];
  const float* bo        = (const float*)d_in[8];
  float* out = (float*)d_out;

  int n = in_sizes[0] / 128;      // 100000
  int E = in_sizes[2] / 2;        // 3200000
  const int* src = edges;
  const int* dst = edges + E;

  auto align_up = [](size_t x) { return (x + 255) & ~(size_t)255; };
  char* p = (char*)d_ws;
  int* csr     = (int*)p;   p += align_up((size_t)E * 4);
  int* rowptr  = (int*)p;   p += align_up((size_t)n * 4);
  int* deg     = (int*)p;   p += align_up((size_t)n * 4);
  float* dis   = (float*)p; p += align_up((size_t)n * 4);
  float* S     = (float*)p; p += align_up((size_t)n * 4);
  int* part    = (int*)p;   p += 8192;   // bCnt[512] | bOff[513] | bCur[512]
  unsigned short* WzP = (unsigned short*)p; p += 32768 * 2;
  unsigned short* WcP = (unsigned short*)p; p += 32768 * 2;
  unsigned short* WoP = (unsigned short*)p; p += 65536 * 2;
  unsigned short* Y  = (unsigned short*)p; p += align_up((size_t)n * 256 * 2);
  char* R = p; p += 2 * align_up((size_t)n * 256 * 2);   // 102.4MB region
  unsigned int* XB   = (unsigned int*)R;    // [N,64] u32 (int8 rows, 25.6MB)
  unsigned short* H  = (unsigned short*)R;  // [N,512] bf16 (102.4MB), aliases XB (dead)
  unsigned short* G3 = Y;                   // [N,128] bf16, aliases Y (dead after gemm1)
  unsigned int* tmpE = (unsigned int*)(R + (size_t)32 * 1024 * 1024); // binned edges,
                                            // 12.8MB, dead before H is written (gemm1)
  int* bCnt = part;
  int* bOff = part + 512;
  int* bCur = part + 1536;
  (void)ws_size; (void)n_in; (void)out_size;

  hipMemsetAsync(bCnt, 0, NBMAX * 4, stream);

  int g4 = (n + 3) / 4;
  int g8 = (n + 7) / 8;
  int gb = (n + 127) / 128;
  int B  = (n + BNODES - 1) >> BSHIFT;
  int gBin = (E + THREADS * EPT - 1) / (THREADS * EPT);

  k_bcount<<<gBin, THREADS, 0, stream>>>(dst, E, bCnt);
  k_bscan<<<1, 512, 0, stream>>>(bCnt, B, bOff, bCur);
  k_bin<<<gBin, THREADS, 0, stream>>>(src, dst, E, n, bOff, bCur, tmpE);
  k_fill2<<<B, 1024, 0, stream>>>(tmpE, bOff, n, deg, dis, rowptr, csr);
  k_tw<<<512, THREADS, 0, stream>>>(Wz, Wc, Wo, WzP, WcP, WoP);

  k_cast<<<g4, THREADS, 0, stream>>>((const float4*)latent, (const float4*)condition,
                                     dis, XB, S, n);
  k_agg1<<<g8, THREADS, 0, stream>>>(XB, S, rowptr, deg, csr, dis, (ushort4*)Y, n, E, 0);
  k_agg1<<<g8, THREADS, 0, stream>>>(XB, S, rowptr, deg, csr, dis, (ushort4*)Y, n, E, 1);
  k_gemm1m<<<gb, THREADS, 0, stream>>>(Y, H, WzP, WcP, bz, bc, n);
  k_gemm2m<<<gb, THREADS, 0, stream>>>(H, WoP, dis, G3, n);
  k_agg2<<<g8, THREADS, 0, stream>>>((const ushort2*)G3, rowptr, deg, csr, dis, bo,
                                     (float2*)out, n);
}

// Round 9
// 581.073 us; speedup vs baseline: 1.1972x; 1.0750x over previous
//
#include <hip/hip_runtime.h>

#define THREADS 256

typedef __attribute__((ext_vector_type(8))) short short8;
typedef __attribute__((ext_vector_type(4))) float f32x4;
#define MFMA16(a, b, c) __builtin_amdgcn_mfma_f32_16x16x32_bf16(a, b, c, 0, 0, 0)

__device__ __forceinline__ unsigned short f2bf(float f) {
  unsigned int u = __float_as_uint(f);
  u += 0x7fffu + ((u >> 16) & 1u);
  return (unsigned short)(u >> 16);
}
__device__ __forceinline__ float bf2f(unsigned short h) {
  return __uint_as_float(((unsigned int)h) << 16);
}
__device__ __forceinline__ float fast_tanh(float x) {
  // bf16-accurate: 1 - 2/(e^{2x}+1)
  float e = __expf(2.0f * x);
  return 1.0f - 2.0f * __builtin_amdgcn_rcpf(e + 1.0f);
}

// ---------------- bucket geometry ----------------
// Packed entry: ((dst & 255) << 17) | src   (src < 2^17 since N = 100000)
#define BSHIFT 8
#define BNODES (1 << BSHIFT)
#define NBMAX 512
#define EPT 16   // edges per thread in binning kernels; CHUNK = 4096
#define EPT2 16  // register-staged entries per thread in k_fill2
#define CAP 15360  // LDS-staged entries (60 KB); bucket mean 8192, sd ~90

// ---------------- pass A: edges per bucket ----------------
__global__ __launch_bounds__(THREADS) void k_bcount(const int* __restrict__ dst, int E,
                                                    int* __restrict__ bCnt) {
  __shared__ int lh[NBMAX];
  int t = threadIdx.x;
  for (int i = t; i < NBMAX; i += THREADS) lh[i] = 0;
  __syncthreads();
  int e0 = blockIdx.x * (THREADS * EPT);
#pragma unroll
  for (int j = 0; j < EPT; ++j) {
    int e = e0 + j * THREADS + t;
    if (e < E) atomicAdd(&lh[dst[e] >> BSHIFT], 1);
  }
  __syncthreads();
  for (int i = t; i < NBMAX; i += THREADS)
    if (lh[i]) atomicAdd(&bCnt[i], lh[i]);
}

// ---------------- pass B: scan bucket counts -> bOff (B+1 entries), zero bCur --------
__global__ __launch_bounds__(512) void k_bscan(const int* __restrict__ bCnt, int B,
                                               int* __restrict__ bOff, int* __restrict__ bCur) {
  __shared__ int sa[512], sb[512];
  int t = threadIdx.x;
  int v = (t < B) ? bCnt[t] : 0;
  sa[t] = v;
  __syncthreads();
  int* cur = sa; int* nxt = sb;
  for (int off = 1; off < 512; off <<= 1) {
    int val = cur[t];
    if (t >= off) val += cur[t - off];
    nxt[t] = val;
    __syncthreads();
    int* z = cur; cur = nxt; nxt = z;
  }
  if (t < B) {
    bOff[t] = cur[t] - v;   // exclusive
    bCur[t] = 0;
    if (t == B - 1) bOff[B] = cur[t];
  }
}

// ---------------- pass C: multi-split edges into bucket-contiguous tmp ---------------
__global__ __launch_bounds__(THREADS) void k_bin(const int* __restrict__ src,
                                                 const int* __restrict__ dst, int E, int n,
                                                 const int* __restrict__ bOff,
                                                 int* __restrict__ bCur,
                                                 unsigned int* __restrict__ tmp) {
  __shared__ int lh[NBMAX];
  __shared__ int gb[NBMAX];
  int t = threadIdx.x;
  int B = (n + BNODES - 1) >> BSHIFT;
  for (int i = t; i < NBMAX; i += THREADS) lh[i] = 0;
  __syncthreads();
  int e0 = blockIdx.x * (THREADS * EPT);
  int b[EPT]; int rk[EPT]; unsigned int v[EPT];
#pragma unroll
  for (int j = 0; j < EPT; ++j) {
    int e = e0 + j * THREADS + t;
    if (e < E) {
      int s = src[e], d = dst[e];
      b[j] = d >> BSHIFT;
      v[j] = ((unsigned int)(d & (BNODES - 1)) << 17) | (unsigned int)s;
      rk[j] = atomicAdd(&lh[b[j]], 1);
    } else {
      b[j] = -1;
    }
  }
  __syncthreads();
  for (int bb = t; bb < B; bb += THREADS) {
    int c = lh[bb];
    if (c > 0) gb[bb] = bOff[bb] + atomicAdd(&bCur[bb], c);
  }
  __syncthreads();
#pragma unroll
  for (int j = 0; j < EPT; ++j)
    if (b[j] >= 0) tmp[gb[b[j]] + rk[j]] = v[j];
}

// ---------------- pass D: per-bucket deg/dis/rowptr + LDS-staged CSR scatter ---------
__global__ __launch_bounds__(1024) void k_fill2(const unsigned int* __restrict__ tmp,
                                                const int* __restrict__ bOff, int n,
                                                int* __restrict__ deg, float* __restrict__ dis,
                                                int* __restrict__ rowptr,
                                                int* __restrict__ csr) {
  __shared__ unsigned int buf[CAP];
  __shared__ int hist[BNODES];
  __shared__ int stmp[BNODES];
  __shared__ int excl[BNODES];
  int b = blockIdx.x;
  int node0 = b << BSHIFT;
  int t = threadIdx.x;
  int beg = bOff[b];
  int end = bOff[b + 1];
  int cnt = end - beg;
  if (t < BNODES) hist[t] = 0;
  __syncthreads();
  unsigned int v[EPT2];
  bool have[EPT2];
  bool inreg = (cnt <= CAP);
  if (inreg) {
#pragma unroll
    for (int j = 0; j < EPT2; ++j) {
      int i = j * 1024 + t;
      have[j] = (i < cnt);
      if (have[j]) {
        v[j] = tmp[beg + i];
        atomicAdd(&hist[v[j] >> 17], 1);
      }
    }
  } else {
    for (int i = t; i < cnt; i += 1024) atomicAdd(&hist[tmp[beg + i] >> 17], 1);
  }
  __syncthreads();
  int myDeg = (t < BNODES) ? hist[t] : 0;
  int* cur = hist; int* nxt = stmp;
  for (int off = 1; off < BNODES; off <<= 1) {
    if (t < BNODES) {
      int val = cur[t];
      if (t >= off) val += cur[t - off];
      nxt[t] = val;
    }
    __syncthreads();
    int* z = cur; cur = nxt; nxt = z;
  }
  if (t < BNODES) {
    int ex = cur[t] - myDeg;
    excl[t] = ex;
    int nd = node0 + t;
    if (nd < n) {
      deg[nd] = myDeg;
      dis[nd] = rsqrtf((float)(myDeg + 1));
      rowptr[nd] = beg + ex;
    }
  }
  __syncthreads();
  if (inreg) {
#pragma unroll
    for (int j = 0; j < EPT2; ++j)
      if (have[j]) {
        int pos = atomicAdd(&excl[v[j] >> 17], 1);
        buf[pos] = v[j] & 0x1FFFFu;
      }
    __syncthreads();
    for (int i = t; i < cnt; i += 1024) csr[beg + i] = (int)buf[i];
  } else {
    for (int i = t; i < cnt; i += 1024) {
      unsigned int u = tmp[beg + i];
      int pos = atomicAdd(&excl[u >> 17], 1);
      csr[beg + pos] = (int)(u & 0x1FFFFu);
    }
  }
}

// ---------------- weight pack: MFMA B-fragment layout, bf16 ----------------
__global__ void k_tw(const float* __restrict__ Wz, const float* __restrict__ Wc,
                     const float* __restrict__ Wo, unsigned short* __restrict__ WzP,
                     unsigned short* __restrict__ WcP, unsigned short* __restrict__ WoP) {
  int t = blockIdx.x * THREADS + threadIdx.x;
  if (t < 32768) {
    int ct = t >> 11, rem = t & 2047;
    int ks = rem >> 9, rem2 = rem & 511;
    int lane = rem2 >> 3, j = rem2 & 7;
    int l16 = lane & 15, quad = lane >> 4;
    int k = ks * 32 + quad * 8 + j;
    int nn = ct * 16 + l16;
    WzP[t] = f2bf(Wz[k * 256 + nn]);
    WcP[t] = f2bf(Wc[k * 256 + nn]);
  } else if (t < 32768 + 65536) {
    int u = t - 32768;
    int ct = u >> 13, rem = u & 8191;
    int kc = rem >> 9, rem2 = rem & 511;
    int lane = rem2 >> 3, j = rem2 & 7;
    int l16 = lane & 15, quad = lane >> 4;
    int k = kc * 32 + quad * 8 + j;
    int nn = ct * 16 + l16;
    WoP[u] = f2bf(Wo[k * 128 + nn]);
  }
}

// ---------------- cast: XB[s] = int8( dis[s]*x / S[s] ) + 128, S = rowmax/127 --------
__global__ void k_cast(const float4* __restrict__ lat4, const float4* __restrict__ con4,
                       const float* __restrict__ dis, unsigned int* __restrict__ XB8,
                       float* __restrict__ S, int n) {
  int tid = threadIdx.x;
  int d = blockIdx.x * 4 + (tid >> 6);
  if (d >= n) return;
  int li = tid & 63;
  float w = dis[d];
  float4 v = (li < 32) ? lat4[(size_t)d * 32 + li] : con4[(size_t)d * 32 + (li - 32)];
  v.x *= w; v.y *= w; v.z *= w; v.w *= w;
  float m = fmaxf(fmaxf(fabsf(v.x), fabsf(v.y)), fmaxf(fabsf(v.z), fabsf(v.w)));
#pragma unroll
  for (int off = 1; off < 64; off <<= 1) m = fmaxf(m, __shfl_xor(m, off, 64));
  m = fmaxf(m, 1e-20f);
  float inv = 127.0f / m;
  unsigned int u0 = (unsigned int)(int)rintf(v.x * inv) + 128u;
  unsigned int u1 = (unsigned int)(int)rintf(v.y * inv) + 128u;
  unsigned int u2 = (unsigned int)(int)rintf(v.z * inv) + 128u;
  unsigned int u3 = (unsigned int)(int)rintf(v.w * inv) + 128u;
  XB8[(size_t)d * 64 + li] = u0 | (u1 << 8) | (u2 << 16) | (u3 << 24);
  if (li == 0) S[d] = m * (1.0f / 127.0f);
}

// ---------------- agg1: Y[d] = bf16( dis[d]*(sum_e x[s] + x[d]) ), x int8+scale -------
// PAIRED-ROW GATHERS: 8B/lane (uint2) so 32 lanes cover a full 256B row; lanes 0-31
// process row d0's edge j while lanes 32-63 process row d1's edge j -> ONE gather
// instruction per TWO edges (halves the request count; bytes/lines unchanged).
// Lane lj owns features lj*8..lj*8+7 of its half-wave's row.
__global__ void k_agg1(const uint2* __restrict__ XB2, const float* __restrict__ S,
                       const int* __restrict__ rowptr, const int* __restrict__ deg,
                       const int* __restrict__ csr, const float* __restrict__ dis,
                       unsigned short* __restrict__ Y, int n, int E) {
  int tid = threadIdx.x;
  int d0v = blockIdx.x * 8 + (tid >> 6) * 2;
  if (d0v >= n) return;
  int d0 = __builtin_amdgcn_readfirstlane(d0v);
  int has1 = (d0 + 1 < n);
  int d1 = has1 ? d0 + 1 : d0;
  int li = tid & 63;
  int hw = li >> 5, lj = li & 31;
  int dh = hw ? d1 : d0;
  int beg0 = __builtin_amdgcn_readfirstlane(rowptr[d0]);
  int cnt0 = __builtin_amdgcn_readfirstlane(deg[d0]);
  int beg1 = __builtin_amdgcn_readfirstlane(rowptr[d1]);
  int cnt1 = has1 ? __builtin_amdgcn_readfirstlane(deg[d1]) : 0;
  int cnth = hw ? cnt1 : cnt0;
  float a0 = 0.f, a1 = 0.f, a2 = 0.f, a3 = 0.f;
  float a4 = 0.f, a5 = 0.f, a6 = 0.f, a7 = 0.f, ssum = 0.f;
  int nbm = cnt0 > cnt1 ? cnt0 : cnt1;
  for (int i = 0; i < nbm; i += 8) {
    int s0[8], s1[8];
#pragma unroll
    for (int j = 0; j < 8; ++j) {
      int i0 = beg0 + i + j; if (i0 > E - 1) i0 = E - 1;
      int i1 = beg1 + i + j; if (i1 > E - 1) i1 = E - 1;
      s0[j] = __builtin_amdgcn_readfirstlane(csr[i0]);
      s1[j] = __builtin_amdgcn_readfirstlane(csr[i1]);
    }
    uint2 v[8]; float sc[8];
#pragma unroll
    for (int j = 0; j < 8; ++j) {
      bool valid = (i + j) < cnth;
      int sv = hw ? s1[j] : s0[j];
      sv = valid ? sv : dh;           // masked -> hot self row (no extra instr)
      v[j] = XB2[(size_t)sv * 32 + lj];
      sc[j] = valid ? S[sv] : 0.f;
    }
#pragma unroll
    for (int j = 0; j < 8; ++j) {
      unsigned int x = v[j].x, y = v[j].y;
      float s = sc[j];
      a0 = fmaf((float)(x & 255u), s, a0);
      a1 = fmaf((float)((x >> 8) & 255u), s, a1);
      a2 = fmaf((float)((x >> 16) & 255u), s, a2);
      a3 = fmaf((float)(x >> 24), s, a3);
      a4 = fmaf((float)(y & 255u), s, a4);
      a5 = fmaf((float)((y >> 8) & 255u), s, a5);
      a6 = fmaf((float)((y >> 16) & 255u), s, a6);
      a7 = fmaf((float)(y >> 24), s, a7);
      ssum += s;
    }
  }
  // self term
  {
    uint2 v = XB2[(size_t)dh * 32 + lj];
    float s = S[dh];
    unsigned int x = v.x, y = v.y;
    a0 = fmaf((float)(x & 255u), s, a0);
    a1 = fmaf((float)((x >> 8) & 255u), s, a1);
    a2 = fmaf((float)((x >> 16) & 255u), s, a2);
    a3 = fmaf((float)(x >> 24), s, a3);
    a4 = fmaf((float)(y & 255u), s, a4);
    a5 = fmaf((float)((y >> 8) & 255u), s, a5);
    a6 = fmaf((float)((y >> 16) & 255u), s, a6);
    a7 = fmaf((float)(y >> 24), s, a7);
    ssum += s;
  }
  float bias = 128.0f * ssum;
  float wd = dis[dh];
  short8 o;
  o[0] = (short)f2bf((a0 - bias) * wd);
  o[1] = (short)f2bf((a1 - bias) * wd);
  o[2] = (short)f2bf((a2 - bias) * wd);
  o[3] = (short)f2bf((a3 - bias) * wd);
  o[4] = (short)f2bf((a4 - bias) * wd);
  o[5] = (short)f2bf((a5 - bias) * wd);
  o[6] = (short)f2bf((a6 - bias) * wd);
  o[7] = (short)f2bf((a7 - bias) * wd);
  if (!hw || has1) *(short8*)(Y + (size_t)dh * 256 + lj * 8) = o;
}

// ---------------- GEMM1 (MFMA): H = tanh([Yz@Wz + bz | Yc@Wc + bc]) bf16 -------------
__global__ __launch_bounds__(THREADS) void k_gemm1m(const unsigned short* __restrict__ Y,
                                                    unsigned short* __restrict__ H,
                                                    const unsigned short* __restrict__ WzP,
                                                    const unsigned short* __restrict__ WcP,
                                                    const float* __restrict__ bz,
                                                    const float* __restrict__ bc, int n) {
  int t = threadIdx.x;
  int wave = t >> 6, lane = t & 63;
  int quad = lane >> 4, l16 = lane & 15;
  int r0 = blockIdx.x * 128 + wave * 32;
  for (int half = 0; half < 2; ++half) {
    const unsigned short* WP = half ? WcP : WzP;
    const float* bias = half ? bc : bz;
    short8 a[2][4];
#pragma unroll
    for (int rg = 0; rg < 2; ++rg) {
      int row = r0 + rg * 16 + l16;
      if (row > n - 1) row = n - 1;
      const unsigned short* yp = Y + (size_t)row * 256 + half * 128 + quad * 8;
#pragma unroll
      for (int ks = 0; ks < 4; ++ks) a[rg][ks] = *(const short8*)(yp + ks * 32);
    }
    for (int ct = 0; ct < 16; ++ct) {
      f32x4 acc0 = {0.f, 0.f, 0.f, 0.f}, acc1 = {0.f, 0.f, 0.f, 0.f};
      const unsigned short* bp = WP + (size_t)(ct * 4) * 512 + lane * 8;
#pragma unroll
      for (int ks = 0; ks < 4; ++ks) {
        short8 b = *(const short8*)(bp + ks * 512);
        acc0 = MFMA16(a[0][ks], b, acc0);
        acc1 = MFMA16(a[1][ks], b, acc1);
      }
      int col = ct * 16 + l16;
      float bb = bias[col];
#pragma unroll
      for (int rg = 0; rg < 2; ++rg) {
        f32x4 ac = rg ? acc1 : acc0;
#pragma unroll
        for (int r = 0; r < 4; ++r) {
          int row = r0 + rg * 16 + quad * 4 + r;
          if (row < n) H[(size_t)row * 512 + half * 256 + col] = f2bf(fast_tanh(ac[r] + bb));
        }
      }
    }
  }
}

// ---------------- GEMM2 (MFMA): G3 = bf16( dis * (H @ Wo) ) --------------------------
__global__ __launch_bounds__(THREADS) void k_gemm2m(const unsigned short* __restrict__ H,
                                                    const unsigned short* __restrict__ WoP,
                                                    const float* __restrict__ dis,
                                                    unsigned short* __restrict__ G3, int n) {
  int t = threadIdx.x;
  int wave = t >> 6, lane = t & 63;
  int quad = lane >> 4, l16 = lane & 15;
  int r0 = blockIdx.x * 128 + wave * 32;
  f32x4 acc[2][8];
#pragma unroll
  for (int rg = 0; rg < 2; ++rg)
#pragma unroll
    for (int ct = 0; ct < 8; ++ct) acc[rg][ct] = (f32x4){0.f, 0.f, 0.f, 0.f};
  int rowA0 = r0 + l16;        if (rowA0 > n - 1) rowA0 = n - 1;
  int rowA1 = r0 + 16 + l16;   if (rowA1 > n - 1) rowA1 = n - 1;
  const unsigned short* hp0 = H + (size_t)rowA0 * 512 + quad * 8;
  const unsigned short* hp1 = H + (size_t)rowA1 * 512 + quad * 8;
  for (int kc = 0; kc < 16; ++kc) {
    short8 a0 = *(const short8*)(hp0 + kc * 32);
    short8 a1 = *(const short8*)(hp1 + kc * 32);
#pragma unroll
    for (int ct = 0; ct < 8; ++ct) {
      short8 b = *(const short8*)(WoP + (size_t)(ct * 16 + kc) * 512 + lane * 8);
      acc[0][ct] = MFMA16(a0, b, acc[0][ct]);
      acc[1][ct] = MFMA16(a1, b, acc[1][ct]);
    }
  }
#pragma unroll
  for (int rg = 0; rg < 2; ++rg)
#pragma unroll
    for (int r = 0; r < 4; ++r) {
      int row = r0 + rg * 16 + quad * 4 + r;
      if (row < n) {
        float dd = dis[row];
#pragma unroll
        for (int ct = 0; ct < 8; ++ct)
          G3[(size_t)row * 128 + ct * 16 + l16] = f2bf(acc[rg][ct][r] * dd);
      }
    }
}

// ---------------- agg2: out[d] = dis[d]*(sum_e G3[s] + G3[d]) + bo, G3 bf16 ------------
// Same paired-row 8B/lane gather structure as k_agg1: lane lj owns features
// lj*4..lj*4+3 (4 bf16 = 8B) of its half-wave's row; one gather = two edges.
__global__ void k_agg2(const uint2* __restrict__ G2x, const int* __restrict__ rowptr,
                       const int* __restrict__ deg, const int* __restrict__ csr,
                       const float* __restrict__ dis, const float* __restrict__ bo,
                       float* __restrict__ out, int n, int E) {
  int tid = threadIdx.x;
  int d0v = blockIdx.x * 8 + (tid >> 6) * 2;
  if (d0v >= n) return;
  int d0 = __builtin_amdgcn_readfirstlane(d0v);
  int has1 = (d0 + 1 < n);
  int d1 = has1 ? d0 + 1 : d0;
  int li = tid & 63;
  int hw = li >> 5, lj = li & 31;
  int dh = hw ? d1 : d0;
  int beg0 = __builtin_amdgcn_readfirstlane(rowptr[d0]);
  int cnt0 = __builtin_amdgcn_readfirstlane(deg[d0]);
  int beg1 = __builtin_amdgcn_readfirstlane(rowptr[d1]);
  int cnt1 = has1 ? __builtin_amdgcn_readfirstlane(deg[d1]) : 0;
  int cnth = hw ? cnt1 : cnt0;
  float a0 = 0.f, a1 = 0.f, a2 = 0.f, a3 = 0.f;
  int nbm = cnt0 > cnt1 ? cnt0 : cnt1;
  for (int i = 0; i < nbm; i += 8) {
    int s0[8], s1[8];
#pragma unroll
    for (int j = 0; j < 8; ++j) {
      int i0 = beg0 + i + j; if (i0 > E - 1) i0 = E - 1;
      int i1 = beg1 + i + j; if (i1 > E - 1) i1 = E - 1;
      s0[j] = __builtin_amdgcn_readfirstlane(csr[i0]);
      s1[j] = __builtin_amdgcn_readfirstlane(csr[i1]);
    }
    uint2 v[8]; float w[8];
#pragma unroll
    for (int j = 0; j < 8; ++j) {
      bool valid = (i + j) < cnth;
      int sv = hw ? s1[j] : s0[j];
      sv = valid ? sv : dh;
      v[j] = G2x[(size_t)sv * 32 + lj];
      w[j] = valid ? 1.0f : 0.0f;
    }
#pragma unroll
    for (int j = 0; j < 8; ++j) {
      unsigned int x = v[j].x, y = v[j].y;
      float ww = w[j];
      a0 = fmaf(bf2f((unsigned short)(x & 0xFFFFu)), ww, a0);
      a1 = fmaf(bf2f((unsigned short)(x >> 16)), ww, a1);
      a2 = fmaf(bf2f((unsigned short)(y & 0xFFFFu)), ww, a2);
      a3 = fmaf(bf2f((unsigned short)(y >> 16)), ww, a3);
    }
  }
  // self term
  {
    uint2 v = G2x[(size_t)dh * 32 + lj];
    a0 += bf2f((unsigned short)(v.x & 0xFFFFu));
    a1 += bf2f((unsigned short)(v.x >> 16));
    a2 += bf2f((unsigned short)(v.y & 0xFFFFu));
    a3 += bf2f((unsigned short)(v.y >> 16));
  }
  float wd = dis[dh];
  float4 bb = *(const float4*)(bo + lj * 4);
  float4 o;
  o.x = a0 * wd + bb.x;
  o.y = a1 * wd + bb.y;
  o.z = a2 * wd + bb.z;
  o.w = a3 * wd + bb.w;
  if (!hw || has1) *(float4*)(out + (size_t)dh * 128 + lj * 4) = o;
}

extern "C" void kernel_launch(void* const* d_in, const int* in_sizes, int n_in,
                              void* d_out, int out_size, void* d_ws, size_t ws_size,
                              hipStream_t stream) {
  const float* latent    = (const float*)d_in[0];
  const float* condition = (const float*)d_in[1];
  const int*   edges     = (const int*)d_in[2];
  const float* Wz        = (const float*)d_in[3];
  const float* bz        = (const float*)d_in[4];
  const float* Wc        = (const float*)d_in[5];
  const float* bc        = (const float*)d_in[6];
  const float* Wo        = (const float*)d_in[7];
  const float* bo        = (const float*)d_in[8];
  float* out = (float*)d_out;

  int n = in_sizes[0] / 128;      // 100000
  int E = in_sizes[2] / 2;        // 3200000
  const int* src = edges;
  const int* dst = edges + E;

  auto align_up = [](size_t x) { return (x + 255) & ~(size_t)255; };
  char* p = (char*)d_ws;
  int* csr     = (int*)p;   p += align_up((size_t)E * 4);
  int* rowptr  = (int*)p;   p += align_up((size_t)n * 4);
  int* deg     = (int*)p;   p += align_up((size_t)n * 4);
  float* dis   = (float*)p; p += align_up((size_t)n * 4);
  float* S     = (float*)p; p += align_up((size_t)n * 4);
  int* part    = (int*)p;   p += 8192;   // bCnt[512] | bOff[513] | bCur[512]
  unsigned short* WzP = (unsigned short*)p; p += 32768 * 2;
  unsigned short* WcP = (unsigned short*)p; p += 32768 * 2;
  unsigned short* WoP = (unsigned short*)p; p += 65536 * 2;
  unsigned short* Y  = (unsigned short*)p; p += align_up((size_t)n * 256 * 2);
  char* R = p; p += 2 * align_up((size_t)n * 256 * 2);   // 102.4MB region
  unsigned int* XB   = (unsigned int*)R;    // [N,64] u32 (int8 rows, 25.6MB)
  unsigned short* H  = (unsigned short*)R;  // [N,512] bf16 (102.4MB), aliases XB (dead)
  unsigned short* G3 = Y;                   // [N,128] bf16, aliases Y (dead after gemm1)
  unsigned int* tmpE = (unsigned int*)(R + (size_t)32 * 1024 * 1024); // binned edges,
                                            // 12.8MB, dead before H is written (gemm1)
  int* bCnt = part;
  int* bOff = part + 512;
  int* bCur = part + 1536;
  (void)ws_size; (void)n_in; (void)out_size;

  hipMemsetAsync(bCnt, 0, NBMAX * 4, stream);

  int g4 = (n + 3) / 4;
  int g8 = (n + 7) / 8;
  int gb = (n + 127) / 128;
  int B  = (n + BNODES - 1) >> BSHIFT;
  int gBin = (E + THREADS * EPT - 1) / (THREADS * EPT);

  k_bcount<<<gBin, THREADS, 0, stream>>>(dst, E, bCnt);
  k_bscan<<<1, 512, 0, stream>>>(bCnt, B, bOff, bCur);
  k_bin<<<gBin, THREADS, 0, stream>>>(src, dst, E, n, bOff, bCur, tmpE);
  k_fill2<<<B, 1024, 0, stream>>>(tmpE, bOff, n, deg, dis, rowptr, csr);
  k_tw<<<512, THREADS, 0, stream>>>(Wz, Wc, Wo, WzP, WcP, WoP);

  k_cast<<<g4, THREADS, 0, stream>>>((const float4*)latent, (const float4*)condition,
                                     dis, XB, S, n);
  k_agg1<<<g8, THREADS, 0, stream>>>((const uint2*)XB, S, rowptr, deg, csr, dis, Y, n, E);
  k_gemm1m<<<gb, THREADS, 0, stream>>>(Y, H, WzP, WcP, bz, bc, n);
  k_gemm2m<<<gb, THREADS, 0, stream>>>(H, WoP, dis, G3, n);
  k_agg2<<<g8, THREADS, 0, stream>>>((const uint2*)G3, rowptr, deg, csr, dis, bo,
                                     out, n, E);
}

// Round 10
// 557.823 us; speedup vs baseline: 1.2471x; 1.0417x over previous
//
#include <hip/hip_runtime.h>

#define THREADS 256

typedef __attribute__((ext_vector_type(8))) short short8;
typedef __attribute__((ext_vector_type(4))) float f32x4;
#define MFMA16(a, b, c) __builtin_amdgcn_mfma_f32_16x16x32_bf16(a, b, c, 0, 0, 0)

__device__ __forceinline__ unsigned short f2bf(float f) {
  unsigned int u = __float_as_uint(f);
  u += 0x7fffu + ((u >> 16) & 1u);
  return (unsigned short)(u >> 16);
}
__device__ __forceinline__ float bf2f(unsigned short h) {
  return __uint_as_float(((unsigned int)h) << 16);
}
__device__ __forceinline__ float fast_tanh(float x) {
  float e = __expf(2.0f * x);
  return 1.0f - 2.0f * __builtin_amdgcn_rcpf(e + 1.0f);
}

// ---------------- bucket geometry ----------------
#define BSHIFT 8
#define BNODES (1 << BSHIFT)
#define NBMAX 512
#define EPT 16
#define EPT2 16
#define CAP 15360

// ---------------- pass A: edges per bucket ----------------
__global__ __launch_bounds__(THREADS) void k_bcount(const int* __restrict__ dst, int E,
                                                    int* __restrict__ bCnt) {
  __shared__ int lh[NBMAX];
  int t = threadIdx.x;
  for (int i = t; i < NBMAX; i += THREADS) lh[i] = 0;
  __syncthreads();
  int e0 = blockIdx.x * (THREADS * EPT);
#pragma unroll
  for (int j = 0; j < EPT; ++j) {
    int e = e0 + j * THREADS + t;
    if (e < E) atomicAdd(&lh[dst[e] >> BSHIFT], 1);
  }
  __syncthreads();
  for (int i = t; i < NBMAX; i += THREADS)
    if (lh[i]) atomicAdd(&bCnt[i], lh[i]);
}

// ---------------- pass B: scan bucket counts ----------------
__global__ __launch_bounds__(512) void k_bscan(const int* __restrict__ bCnt, int B,
                                               int* __restrict__ bOff, int* __restrict__ bCur) {
  __shared__ int sa[512], sb[512];
  int t = threadIdx.x;
  int v = (t < B) ? bCnt[t] : 0;
  sa[t] = v;
  __syncthreads();
  int* cur = sa; int* nxt = sb;
  for (int off = 1; off < 512; off <<= 1) {
    int val = cur[t];
    if (t >= off) val += cur[t - off];
    nxt[t] = val;
    __syncthreads();
    int* z = cur; cur = nxt; nxt = z;
  }
  if (t < B) {
    bOff[t] = cur[t] - v;
    bCur[t] = 0;
    if (t == B - 1) bOff[B] = cur[t];
  }
}

// ---------------- pass C: multi-split ----------------
__global__ __launch_bounds__(THREADS) void k_bin(const int* __restrict__ src,
                                                 const int* __restrict__ dst, int E, int n,
                                                 const int* __restrict__ bOff,
                                                 int* __restrict__ bCur,
                                                 unsigned int* __restrict__ tmp) {
  __shared__ int lh[NBMAX];
  __shared__ int gb[NBMAX];
  int t = threadIdx.x;
  int B = (n + BNODES - 1) >> BSHIFT;
  for (int i = t; i < NBMAX; i += THREADS) lh[i] = 0;
  __syncthreads();
  int e0 = blockIdx.x * (THREADS * EPT);
  int b[EPT]; int rk[EPT]; unsigned int v[EPT];
#pragma unroll
  for (int j = 0; j < EPT; ++j) {
    int e = e0 + j * THREADS + t;
    if (e < E) {
      int s = src[e], d = dst[e];
      b[j] = d >> BSHIFT;
      v[j] = ((unsigned int)(d & (BNODES - 1)) << 17) | (unsigned int)s;
      rk[j] = atomicAdd(&lh[b[j]], 1);
    } else {
      b[j] = -1;
    }
  }
  __syncthreads();
  for (int bb = t; bb < B; bb += THREADS) {
    int c = lh[bb];
    if (c > 0) gb[bb] = bOff[bb] + atomicAdd(&bCur[bb], c);
  }
  __syncthreads();
#pragma unroll
  for (int j = 0; j < EPT; ++j)
    if (b[j] >= 0) tmp[gb[b[j]] + rk[j]] = v[j];
}

// ---------------- pass D: per-bucket deg/dis/rowptr + LDS-staged CSR scatter ---------
__global__ __launch_bounds__(1024) void k_fill2(const unsigned int* __restrict__ tmp,
                                                const int* __restrict__ bOff, int n,
                                                int* __restrict__ deg, float* __restrict__ dis,
                                                int* __restrict__ rowptr,
                                                int* __restrict__ csr) {
  __shared__ unsigned int buf[CAP];
  __shared__ int hist[BNODES];
  __shared__ int stmp[BNODES];
  __shared__ int excl[BNODES];
  int b = blockIdx.x;
  int node0 = b << BSHIFT;
  int t = threadIdx.x;
  int beg = bOff[b];
  int end = bOff[b + 1];
  int cnt = end - beg;
  if (t < BNODES) hist[t] = 0;
  __syncthreads();
  unsigned int v[EPT2];
  bool have[EPT2];
  bool inreg = (cnt <= CAP);
  if (inreg) {
#pragma unroll
    for (int j = 0; j < EPT2; ++j) {
      int i = j * 1024 + t;
      have[j] = (i < cnt);
      if (have[j]) {
        v[j] = tmp[beg + i];
        atomicAdd(&hist[v[j] >> 17], 1);
      }
    }
  } else {
    for (int i = t; i < cnt; i += 1024) atomicAdd(&hist[tmp[beg + i] >> 17], 1);
  }
  __syncthreads();
  int myDeg = (t < BNODES) ? hist[t] : 0;
  int* cur = hist; int* nxt = stmp;
  for (int off = 1; off < BNODES; off <<= 1) {
    if (t < BNODES) {
      int val = cur[t];
      if (t >= off) val += cur[t - off];
      nxt[t] = val;
    }
    __syncthreads();
    int* z = cur; cur = nxt; nxt = z;
  }
  if (t < BNODES) {
    int ex = cur[t] - myDeg;
    excl[t] = ex;
    int nd = node0 + t;
    if (nd < n) {
      deg[nd] = myDeg;
      dis[nd] = rsqrtf((float)(myDeg + 1));
      rowptr[nd] = beg + ex;
    }
  }
  __syncthreads();
  if (inreg) {
#pragma unroll
    for (int j = 0; j < EPT2; ++j)
      if (have[j]) {
        int pos = atomicAdd(&excl[v[j] >> 17], 1);
        buf[pos] = v[j] & 0x1FFFFu;
      }
    __syncthreads();
    for (int i = t; i < cnt; i += 1024) csr[beg + i] = (int)buf[i];
  } else {
    for (int i = t; i < cnt; i += 1024) {
      unsigned int u = tmp[beg + i];
      int pos = atomicAdd(&excl[u >> 17], 1);
      csr[beg + pos] = (int)(u & 0x1FFFFu);
    }
  }
}

// ---------------- weight pack ----------------
__global__ void k_tw(const float* __restrict__ Wz, const float* __restrict__ Wc,
                     const float* __restrict__ Wo, unsigned short* __restrict__ WzP,
                     unsigned short* __restrict__ WcP, unsigned short* __restrict__ WoP) {
  int t = blockIdx.x * THREADS + threadIdx.x;
  if (t < 32768) {
    int ct = t >> 11, rem = t & 2047;
    int ks = rem >> 9, rem2 = rem & 511;
    int lane = rem2 >> 3, j = rem2 & 7;
    int l16 = lane & 15, quad = lane >> 4;
    int k = ks * 32 + quad * 8 + j;
    int nn = ct * 16 + l16;
    WzP[t] = f2bf(Wz[k * 256 + nn]);
    WcP[t] = f2bf(Wc[k * 256 + nn]);
  } else if (t < 32768 + 65536) {
    int u = t - 32768;
    int ct = u >> 13, rem = u & 8191;
    int kc = rem >> 9, rem2 = rem & 511;
    int lane = rem2 >> 3, j = rem2 & 7;
    int l16 = lane & 15, quad = lane >> 4;
    int k = kc * 32 + quad * 8 + j;
    int nn = ct * 16 + l16;
    WoP[u] = f2bf(Wo[k * 128 + nn]);
  }
}

// ---------------- cast ----------------
__global__ void k_cast(const float4* __restrict__ lat4, const float4* __restrict__ con4,
                       const float* __restrict__ dis, unsigned int* __restrict__ XB8,
                       float* __restrict__ S, int n) {
  int tid = threadIdx.x;
  int d = blockIdx.x * 4 + (tid >> 6);
  if (d >= n) return;
  int li = tid & 63;
  float w = dis[d];
  float4 v = (li < 32) ? lat4[(size_t)d * 32 + li] : con4[(size_t)d * 32 + (li - 32)];
  v.x *= w; v.y *= w; v.z *= w; v.w *= w;
  float m = fmaxf(fmaxf(fabsf(v.x), fabsf(v.y)), fmaxf(fabsf(v.z), fabsf(v.w)));
#pragma unroll
  for (int off = 1; off < 64; off <<= 1) m = fmaxf(m, __shfl_xor(m, off, 64));
  m = fmaxf(m, 1e-20f);
  float inv = 127.0f / m;
  unsigned int u0 = (unsigned int)(int)rintf(v.x * inv) + 128u;
  unsigned int u1 = (unsigned int)(int)rintf(v.y * inv) + 128u;
  unsigned int u2 = (unsigned int)(int)rintf(v.z * inv) + 128u;
  unsigned int u3 = (unsigned int)(int)rintf(v.w * inv) + 128u;
  XB8[(size_t)d * 64 + li] = u0 | (u1 << 8) | (u2 << 16) | (u3 << 24);
  if (li == 0) S[d] = m * (1.0f / 127.0f);
}

// ---------------- agg1: paired-row 8B/lane gathers (round-9 structure, unchanged) ----
__global__ void k_agg1(const uint2* __restrict__ XB2, const float* __restrict__ S,
                       const int* __restrict__ rowptr, const int* __restrict__ deg,
                       const int* __restrict__ csr, const float* __restrict__ dis,
                       unsigned short* __restrict__ Y, int n, int E) {
  int tid = threadIdx.x;
  int d0v = blockIdx.x * 8 + (tid >> 6) * 2;
  if (d0v >= n) return;
  int d0 = __builtin_amdgcn_readfirstlane(d0v);
  int has1 = (d0 + 1 < n);
  int d1 = has1 ? d0 + 1 : d0;
  int li = tid & 63;
  int hw = li >> 5, lj = li & 31;
  int dh = hw ? d1 : d0;
  int beg0 = __builtin_amdgcn_readfirstlane(rowptr[d0]);
  int cnt0 = __builtin_amdgcn_readfirstlane(deg[d0]);
  int beg1 = __builtin_amdgcn_readfirstlane(rowptr[d1]);
  int cnt1 = has1 ? __builtin_amdgcn_readfirstlane(deg[d1]) : 0;
  int cnth = hw ? cnt1 : cnt0;
  float a0 = 0.f, a1 = 0.f, a2 = 0.f, a3 = 0.f;
  float a4 = 0.f, a5 = 0.f, a6 = 0.f, a7 = 0.f, ssum = 0.f;
  int nbm = cnt0 > cnt1 ? cnt0 : cnt1;
  for (int i = 0; i < nbm; i += 8) {
    int s0[8], s1[8];
#pragma unroll
    for (int j = 0; j < 8; ++j) {
      int i0 = beg0 + i + j; if (i0 > E - 1) i0 = E - 1;
      int i1 = beg1 + i + j; if (i1 > E - 1) i1 = E - 1;
      s0[j] = __builtin_amdgcn_readfirstlane(csr[i0]);
      s1[j] = __builtin_amdgcn_readfirstlane(csr[i1]);
    }
    uint2 v[8]; float sc[8];
#pragma unroll
    for (int j = 0; j < 8; ++j) {
      bool valid = (i + j) < cnth;
      int sv = hw ? s1[j] : s0[j];
      sv = valid ? sv : dh;
      v[j] = XB2[(size_t)sv * 32 + lj];
      sc[j] = valid ? S[sv] : 0.f;
    }
#pragma unroll
    for (int j = 0; j < 8; ++j) {
      unsigned int x = v[j].x, y = v[j].y;
      float s = sc[j];
      a0 = fmaf((float)(x & 255u), s, a0);
      a1 = fmaf((float)((x >> 8) & 255u), s, a1);
      a2 = fmaf((float)((x >> 16) & 255u), s, a2);
      a3 = fmaf((float)(x >> 24), s, a3);
      a4 = fmaf((float)(y & 255u), s, a4);
      a5 = fmaf((float)((y >> 8) & 255u), s, a5);
      a6 = fmaf((float)((y >> 16) & 255u), s, a6);
      a7 = fmaf((float)(y >> 24), s, a7);
      ssum += s;
    }
  }
  // self term
  {
    uint2 v = XB2[(size_t)dh * 32 + lj];
    float s = S[dh];
    unsigned int x = v.x, y = v.y;
    a0 = fmaf((float)(x & 255u), s, a0);
    a1 = fmaf((float)((x >> 8) & 255u), s, a1);
    a2 = fmaf((float)((x >> 16) & 255u), s, a2);
    a3 = fmaf((float)(x >> 24), s, a3);
    a4 = fmaf((float)(y & 255u), s, a4);
    a5 = fmaf((float)((y >> 8) & 255u), s, a5);
    a6 = fmaf((float)((y >> 16) & 255u), s, a6);
    a7 = fmaf((float)(y >> 24), s, a7);
    ssum += s;
  }
  float bias = 128.0f * ssum;
  float wd = dis[dh];
  short8 o;
  o[0] = (short)f2bf((a0 - bias) * wd);
  o[1] = (short)f2bf((a1 - bias) * wd);
  o[2] = (short)f2bf((a2 - bias) * wd);
  o[3] = (short)f2bf((a3 - bias) * wd);
  o[4] = (short)f2bf((a4 - bias) * wd);
  o[5] = (short)f2bf((a5 - bias) * wd);
  o[6] = (short)f2bf((a6 - bias) * wd);
  o[7] = (short)f2bf((a7 - bias) * wd);
  if (!hw || has1) *(short8*)(Y + (size_t)dh * 256 + lj * 8) = o;
}

// ---------------- GEMM1 (MFMA) ----------------
__global__ __launch_bounds__(THREADS) void k_gemm1m(const unsigned short* __restrict__ Y,
                                                    unsigned short* __restrict__ H,
                                                    const unsigned short* __restrict__ WzP,
                                                    const unsigned short* __restrict__ WcP,
                                                    const float* __restrict__ bz,
                                                    const float* __restrict__ bc, int n) {
  int t = threadIdx.x;
  int wave = t >> 6, lane = t & 63;
  int quad = lane >> 4, l16 = lane & 15;
  int r0 = blockIdx.x * 128 + wave * 32;
  for (int half = 0; half < 2; ++half) {
    const unsigned short* WP = half ? WcP : WzP;
    const float* bias = half ? bc : bz;
    short8 a[2][4];
#pragma unroll
    for (int rg = 0; rg < 2; ++rg) {
      int row = r0 + rg * 16 + l16;
      if (row > n - 1) row = n - 1;
      const unsigned short* yp = Y + (size_t)row * 256 + half * 128 + quad * 8;
#pragma unroll
      for (int ks = 0; ks < 4; ++ks) a[rg][ks] = *(const short8*)(yp + ks * 32);
    }
    for (int ct = 0; ct < 16; ++ct) {
      f32x4 acc0 = {0.f, 0.f, 0.f, 0.f}, acc1 = {0.f, 0.f, 0.f, 0.f};
      const unsigned short* bp = WP + (size_t)(ct * 4) * 512 + lane * 8;
#pragma unroll
      for (int ks = 0; ks < 4; ++ks) {
        short8 b = *(const short8*)(bp + ks * 512);
        acc0 = MFMA16(a[0][ks], b, acc0);
        acc1 = MFMA16(a[1][ks], b, acc1);
      }
      int col = ct * 16 + l16;
      float bb = bias[col];
#pragma unroll
      for (int rg = 0; rg < 2; ++rg) {
        f32x4 ac = rg ? acc1 : acc0;
#pragma unroll
        for (int r = 0; r < 4; ++r) {
          int row = r0 + rg * 16 + quad * 4 + r;
          if (row < n) H[(size_t)row * 512 + half * 256 + col] = f2bf(fast_tanh(ac[r] + bb));
        }
      }
    }
  }
}

// ---------------- GEMM2 (MFMA) + int8 row-quantized G8 epilogue ----------------------
// G8[row] = int8 of dis[row]*(H@Wo) in PERMUTED byte order: byte b = l16*8 + ct holds
// feature f = ct*16 + l16 = (b&7)*16 + (b>>3). S2[row] = rowmax/127. Row absmax via
// 16-lane shfl_xor (l16 group shares quad). agg2 un-permutes at the final store.
__global__ __launch_bounds__(THREADS) void k_gemm2m(const unsigned short* __restrict__ H,
                                                    const unsigned short* __restrict__ WoP,
                                                    const float* __restrict__ dis,
                                                    unsigned char* __restrict__ G8,
                                                    float* __restrict__ S2, int n) {
  int t = threadIdx.x;
  int wave = t >> 6, lane = t & 63;
  int quad = lane >> 4, l16 = lane & 15;
  int r0 = blockIdx.x * 128 + wave * 32;
  f32x4 acc[2][8];
#pragma unroll
  for (int rg = 0; rg < 2; ++rg)
#pragma unroll
    for (int ct = 0; ct < 8; ++ct) acc[rg][ct] = (f32x4){0.f, 0.f, 0.f, 0.f};
  int rowA0 = r0 + l16;        if (rowA0 > n - 1) rowA0 = n - 1;
  int rowA1 = r0 + 16 + l16;   if (rowA1 > n - 1) rowA1 = n - 1;
  const unsigned short* hp0 = H + (size_t)rowA0 * 512 + quad * 8;
  const unsigned short* hp1 = H + (size_t)rowA1 * 512 + quad * 8;
  for (int kc = 0; kc < 16; ++kc) {
    short8 a0 = *(const short8*)(hp0 + kc * 32);
    short8 a1 = *(const short8*)(hp1 + kc * 32);
#pragma unroll
    for (int ct = 0; ct < 8; ++ct) {
      short8 b = *(const short8*)(WoP + (size_t)(ct * 16 + kc) * 512 + lane * 8);
      acc[0][ct] = MFMA16(a0, b, acc[0][ct]);
      acc[1][ct] = MFMA16(a1, b, acc[1][ct]);
    }
  }
#pragma unroll
  for (int rg = 0; rg < 2; ++rg)
#pragma unroll
    for (int r = 0; r < 4; ++r) {
      int row = r0 + rg * 16 + quad * 4 + r;
      int rc = row < n ? row : n - 1;
      float dd = dis[rc];
      float vals[8]; float m = 0.f;
#pragma unroll
      for (int ct = 0; ct < 8; ++ct) {
        vals[ct] = acc[rg][ct][r] * dd;
        m = fmaxf(m, fabsf(vals[ct]));
      }
#pragma unroll
      for (int off = 1; off < 16; off <<= 1) m = fmaxf(m, __shfl_xor(m, off, 64));
      m = fmaxf(m, 1e-20f);
      float inv = 127.0f / m;
      unsigned int u0 = 0, u1 = 0;
#pragma unroll
      for (int k = 0; k < 4; ++k) {
        int q = (int)rintf(vals[k] * inv);
        u0 |= ((unsigned int)(q & 255)) << (8 * k);
      }
#pragma unroll
      for (int k = 0; k < 4; ++k) {
        int q = (int)rintf(vals[4 + k] * inv);
        u1 |= ((unsigned int)(q & 255)) << (8 * k);
      }
      if (row < n) {
        uint2 pk; pk.x = u0; pk.y = u1;
        *(uint2*)(G8 + (size_t)row * 128 + l16 * 8) = pk;
        if (l16 == 0) S2[row] = m * (1.0f / 127.0f);
      }
    }
}

// ---------------- agg2: int8 G8 gathers (128B/row, 1 dword/lane, paired rows) --------
// Lane lj reads bytes lj*4..lj*4+3 -> features f = ((lj&1)*4+k)*16 + (lj>>1).
__global__ void k_agg2(const unsigned int* __restrict__ G8, const float* __restrict__ S2,
                       const int* __restrict__ rowptr, const int* __restrict__ deg,
                       const int* __restrict__ csr, const float* __restrict__ dis,
                       const float* __restrict__ bo, float* __restrict__ out, int n, int E) {
  int tid = threadIdx.x;
  int d0v = blockIdx.x * 8 + (tid >> 6) * 2;
  if (d0v >= n) return;
  int d0 = __builtin_amdgcn_readfirstlane(d0v);
  int has1 = (d0 + 1 < n);
  int d1 = has1 ? d0 + 1 : d0;
  int li = tid & 63;
  int hw = li >> 5, lj = li & 31;
  int dh = hw ? d1 : d0;
  int beg0 = __builtin_amdgcn_readfirstlane(rowptr[d0]);
  int cnt0 = __builtin_amdgcn_readfirstlane(deg[d0]);
  int beg1 = __builtin_amdgcn_readfirstlane(rowptr[d1]);
  int cnt1 = has1 ? __builtin_amdgcn_readfirstlane(deg[d1]) : 0;
  int cnth = hw ? cnt1 : cnt0;
  float a0 = 0.f, a1 = 0.f, a2 = 0.f, a3 = 0.f;
  int nbm = cnt0 > cnt1 ? cnt0 : cnt1;
  for (int i = 0; i < nbm; i += 8) {
    int s0[8], s1[8];
#pragma unroll
    for (int j = 0; j < 8; ++j) {
      int i0 = beg0 + i + j; if (i0 > E - 1) i0 = E - 1;
      int i1 = beg1 + i + j; if (i1 > E - 1) i1 = E - 1;
      s0[j] = __builtin_amdgcn_readfirstlane(csr[i0]);
      s1[j] = __builtin_amdgcn_readfirstlane(csr[i1]);
    }
    unsigned int v[8]; float sc[8];
#pragma unroll
    for (int j = 0; j < 8; ++j) {
      bool valid = (i + j) < cnth;
      int sv = hw ? s1[j] : s0[j];
      sv = valid ? sv : dh;
      v[j] = G8[(size_t)sv * 32 + lj];
      sc[j] = valid ? S2[sv] : 0.f;
    }
#pragma unroll
    for (int j = 0; j < 8; ++j) {
      unsigned int x = v[j];
      float s = sc[j];
      a0 = fmaf((float)((int)(x << 24) >> 24), s, a0);
      a1 = fmaf((float)((int)(x << 16) >> 24), s, a1);
      a2 = fmaf((float)((int)(x << 8) >> 24), s, a2);
      a3 = fmaf((float)((int)x >> 24), s, a3);
    }
  }
  // self term
  {
    unsigned int x = G8[(size_t)dh * 32 + lj];
    float s = S2[dh];
    a0 = fmaf((float)((int)(x << 24) >> 24), s, a0);
    a1 = fmaf((float)((int)(x << 16) >> 24), s, a1);
    a2 = fmaf((float)((int)(x << 8) >> 24), s, a2);
    a3 = fmaf((float)((int)x >> 24), s, a3);
  }
  if (hw && !has1) return;
  float wd = dis[dh];
  int fbase = (lj & 1) * 4;
  int fcol = lj >> 1;
  float r0v = a0 * wd + bo[(fbase + 0) * 16 + fcol];
  float r1v = a1 * wd + bo[(fbase + 1) * 16 + fcol];
  float r2v = a2 * wd + bo[(fbase + 2) * 16 + fcol];
  float r3v = a3 * wd + bo[(fbase + 3) * 16 + fcol];
  float* op = out + (size_t)dh * 128 + fcol;
  op[(fbase + 0) * 16] = r0v;
  op[(fbase + 1) * 16] = r1v;
  op[(fbase + 2) * 16] = r2v;
  op[(fbase + 3) * 16] = r3v;
}

extern "C" void kernel_launch(void* const* d_in, const int* in_sizes, int n_in,
                              void* d_out, int out_size, void* d_ws, size_t ws_size,
                              hipStream_t stream) {
  const float* latent    = (const float*)d_in[0];
  const float* condition = (const float*)d_in[1];
  const int*   edges     = (const int*)d_in[2];
  const float* Wz        = (const float*)d_in[3];
  const float* bz        = (const float*)d_in[4];
  const float* Wc        = (const float*)d_in[5];
  const float* bc        = (const float*)d_in[6];
  const float* Wo        = (const float*)d_in[7];
  const float* bo        = (const float*)d_in[8];
  float* out = (float*)d_out;

  int n = in_sizes[0] / 128;      // 100000
  int E = in_sizes[2] / 2;        // 3200000
  const int* src = edges;
  const int* dst = edges + E;

  auto align_up = [](size_t x) { return (x + 255) & ~(size_t)255; };
  char* p = (char*)d_ws;
  int* csr     = (int*)p;   p += align_up((size_t)E * 4);
  int* rowptr  = (int*)p;   p += align_up((size_t)n * 4);
  int* deg     = (int*)p;   p += align_up((size_t)n * 4);
  float* dis   = (float*)p; p += align_up((size_t)n * 4);
  float* S     = (float*)p; p += align_up((size_t)n * 4);
  int* part    = (int*)p;   p += 8192;
  unsigned short* WzP = (unsigned short*)p; p += 32768 * 2;
  unsigned short* WcP = (unsigned short*)p; p += 32768 * 2;
  unsigned short* WoP = (unsigned short*)p; p += 65536 * 2;
  unsigned short* Y  = (unsigned short*)p; p += align_up((size_t)n * 256 * 2);
  char* R = p; p += 2 * align_up((size_t)n * 256 * 2);   // 102.4MB region
  unsigned int* XB   = (unsigned int*)R;    // [N,64] u32 (int8 rows, 25.6MB)
  unsigned short* H  = (unsigned short*)R;  // [N,512] bf16, aliases XB (dead)
  unsigned char* G8  = (unsigned char*)Y;   // [N,128] int8, aliases Y (dead after gemm1)
  float* S2 = S;                            // per-row G3 scale, aliases S (dead after agg1)
  unsigned int* tmpE = (unsigned int*)(R + (size_t)32 * 1024 * 1024);
  int* bCnt = part;
  int* bOff = part + 512;
  int* bCur = part + 1536;
  (void)ws_size; (void)n_in; (void)out_size;

  hipMemsetAsync(bCnt, 0, NBMAX * 4, stream);

  int g4 = (n + 3) / 4;
  int g8 = (n + 7) / 8;
  int gb = (n + 127) / 128;
  int B  = (n + BNODES - 1) >> BSHIFT;
  int gBin = (E + THREADS * EPT - 1) / (THREADS * EPT);

  k_bcount<<<gBin, THREADS, 0, stream>>>(dst, E, bCnt);
  k_bscan<<<1, 512, 0, stream>>>(bCnt, B, bOff, bCur);
  k_bin<<<gBin, THREADS, 0, stream>>>(src, dst, E, n, bOff, bCur, tmpE);
  k_fill2<<<B, 1024, 0, stream>>>(tmpE, bOff, n, deg, dis, rowptr, csr);
  k_tw<<<512, THREADS, 0, stream>>>(Wz, Wc, Wo, WzP, WcP, WoP);

  k_cast<<<g4, THREADS, 0, stream>>>((const float4*)latent, (const float4*)condition,
                                     dis, XB, S, n);
  k_agg1<<<g8, THREADS, 0, stream>>>((const uint2*)XB, S, rowptr, deg, csr, dis, Y, n, E);
  k_gemm1m<<<gb, THREADS, 0, stream>>>(Y, H, WzP, WcP, bz, bc, n);
  k_gemm2m<<<gb, THREADS, 0, stream>>>(H, WoP, dis, G8, S2, n);
  k_agg2<<<g8, THREADS, 0, stream>>>((const unsigned int*)G8, S2, rowptr, deg, csr, dis,
                                     bo, out, n, E);
}